// Round 7
// baseline (604.798 us; speedup 1.0000x reference)
//
#include <hip/hip_runtime.h>

typedef unsigned short ushort_t;
typedef unsigned long long u64_t;
typedef __attribute__((ext_vector_type(8))) __bf16 bf16x8;
typedef __attribute__((ext_vector_type(4))) float f32x4;
typedef __attribute__((ext_vector_type(4))) unsigned int uint4v;

#define T_TOTAL 65536
#define NLAYERS 20
#define OUT_START 2047
#define OUT_W 63489
#define NBLOCKS 512

// workspace layout
#define PBF_PER_LAYER 24576
#define PBF_LAYERS (NLAYERS * PBF_PER_LAYER)        // 491520
#define PBF_TOTAL (PBF_LAYERS + 4096 + 16384)       // 512000 ushorts = 256000 floats
#define H0_OFF 524288
#define HBUF (64 * T_TOTAL)                          // [tau][ch] fp32
#define H1_OFF (H0_OFF + HBUF)
#define FLAG_OFF (H1_OFF + HBUF)                     // 512 flags, 128B apart (64KB)

__device__ __forceinline__ ushort_t f2bf(float x) {
    union { float f; unsigned u; } c; c.f = x;
    unsigned u = c.u + 0x7FFFu + ((c.u >> 16) & 1u);   // RNE
    return (ushort_t)(u >> 16);
}

union BF8 { uint4v u4; bf16x8 v; };

__device__ __forceinline__ bf16x8 cvt8(f32x4 a, f32x4 b) {
    union { unsigned u[4]; bf16x8 v; } r;
    r.u[0] = (unsigned)f2bf(a[0]) | ((unsigned)f2bf(a[1]) << 16);
    r.u[1] = (unsigned)f2bf(a[2]) | ((unsigned)f2bf(a[3]) << 16);
    r.u[2] = (unsigned)f2bf(b[0]) | ((unsigned)f2bf(b[1]) << 16);
    r.u[3] = (unsigned)f2bf(b[2]) | ((unsigned)f2bf(b[3]) << 16);
    return r.v;
}

// ---------------------------------------------------------------- pack ALL MFMA weights (bf16, A-fragment order)
__global__ __launch_bounds__(256) void pack_mfma(
    const float* __restrict__ wf, const float* __restrict__ wg,
    const float* __restrict__ wr, const float* __restrict__ wsk,
    const float* __restrict__ w0h, const float* __restrict__ w1h,
    ushort_t* __restrict__ out, unsigned* __restrict__ flags)
{
    int idx = blockIdx.x * 256 + threadIdx.x;
    if (idx < NBLOCKS) flags[idx << 5] = 0u;   // reset progress flags every launch (replay-safe)
    if (idx >= PBF_TOTAL) return;
    float v;
    if (idx < PBF_LAYERS) {
        int i = idx / PBF_PER_LAYER;
        int r = idx - i * PBF_PER_LAYER;
        if (r < 16384) {                  // gates A (128x128 = [f;g] x [left||right])
            int j = r & 7, l = (r >> 3) & 63, ks = (r >> 9) & 3, mt = r >> 11;
            int m = mt * 16 + (l & 15);
            int k = ks * 32 + ((l >> 4) << 3) + j;
            int o = m & 63, c = k & 63, half = k >> 6;
            const float* src = (m < 64) ? wf : wg;
            v = src[(((i * 64 + o) * 64 + c) << 1) + half];
        } else {                          // rs A (128x64 = [r;s] x c)
            int rr = r - 16384;
            int j = rr & 7, l = (rr >> 3) & 63, ks = (rr >> 9) & 1, mt = rr >> 10;
            int m = mt * 16 + (l & 15);
            int k = ks * 32 + ((l >> 4) << 3) + j;
            v = (m < 64) ? wr[(i * 64 + m) * 64 + k] : wsk[(i * 64 + (m - 64)) * 64 + k];
        }
    } else if (idx < PBF_LAYERS + 4096) { // W0 head (64x64)
        int rr = idx - PBF_LAYERS;
        int j = rr & 7, l = (rr >> 3) & 63, ks = (rr >> 9) & 1, mt = rr >> 10;
        int m = mt * 16 + (l & 15);
        int k = ks * 32 + ((l >> 4) << 3) + j;
        v = w0h[m * 64 + k];
    } else {                              // W1 head (256x64)
        int rr = idx - PBF_LAYERS - 4096;
        int j = rr & 7, l = (rr >> 3) & 63, ks = (rr >> 9) & 1, mt = rr >> 10;
        int m = mt * 16 + (l & 15);
        int k = ks * 32 + ((l >> 4) << 3) + j;
        v = w1h[m * 64 + k];
    }
    out[idx] = f2bf(v);
}

// ---------------------------------------------------------------- fused persistent kernel
// R7: 512 blocks x 512 threads (8 waves). R6 counters showed latency-bound at
// 2 waves/SIMD (all pipes <24%); now 2 blocks/CU x 8 waves = 4 waves/SIMD.
// Each wave owns ONE 16-row tile (was two) -> per-wave serial chain halved.
// Residual loads are issued WITH the gate loads and waited with counted
// vmcnt(4) -> the second LLC round-trip per layer hides under the gates GEMM.
// Sync design unchanged from R6 (proven): fence-free sc1/LLC H exchange +
// relaxed neighbor progress flags; weights stay L2-cached (no inv/wbl2 ever).
__global__ __launch_bounds__(512, 4) void wavenet_fused(
    const float* __restrict__ in, const float* __restrict__ w0v, const float* __restrict__ b0v,
    const ushort_t* __restrict__ pbf,
    const float* __restrict__ bf_all, const float* __restrict__ bg_all,
    const float* __restrict__ br_all, const float* __restrict__ bs_all,
    const float* __restrict__ alpha, const float* __restrict__ b_out0,
    const float* __restrict__ b_out1,
    float* __restrict__ HA, float* __restrict__ HB, float* __restrict__ out,
    unsigned* flags)
{
    __shared__ alignas(16) ushort_t ZB[128 * 72];
    __shared__ alignas(16) ushort_t YB[128 * 72];

    const int tid = threadIdx.x;
    const int l = tid & 63, w = tid >> 6;          // 8 waves
    const int l15 = l & 15, quad = l >> 4;
    const int bid = (int)blockIdx.x;
    const int blk = (bid & 7) * 64 + (bid >> 3);   // XCD-chunked swizzle
    const int tau0 = blk * 128;
    const int tauW = tau0 + w * 16 + l15;          // this wave's single 16-row tile
    const int nloc = w * 16 + l15;                 // row index within block (0..127)

    // ---- init h0 for own chunk: H[tau][ch] = w0[ch]*in[tau] + b0[ch] (sc1 -> LLC)
    #pragma unroll
    for (int it = 0; it < 4; ++it) {
        int idx = (it << 9) + tid;           // 0..2047 f32x4-slots
        int trow = idx >> 4, c4 = (idx & 15) << 2;
        float x = in[tau0 + trow];
        f32x4 wv = *(const f32x4*)(w0v + c4);
        f32x4 bv = *(const f32x4*)(b0v + c4);
        f32x4 v;
        #pragma unroll
        for (int r = 0; r < 4; ++r) v[r] = fmaf(wv[r], x, bv[r]);
        float* dst = HA + (tau0 + trow) * 64 + c4;
        asm volatile("global_store_dwordx4 %0, %1, off sc1" :: "v"(dst), "v"(v) : "memory");
    }
    asm volatile("s_waitcnt vmcnt(0)" ::: "memory");
    __syncthreads();
    if (tid == 0)
        __hip_atomic_store(&flags[blk << 5], 1u, __ATOMIC_RELAXED, __HIP_MEMORY_SCOPE_AGENT);

    f32x4 skip_acc[4];
    #pragma unroll
    for (int mt = 0; mt < 4; ++mt) skip_acc[mt] = (f32x4){0.0f, 0.0f, 0.0f, 0.0f};

    float* Hin = HA;
    float* Hout = HB;

    #pragma unroll 1
    for (int i = 0; i < NLAYERS; ++i) {
        const int d = 1 << (i >= 10 ? i - 10 : i);
        const int dprev = (i == 0) ? 0 : (1 << ((i - 1) >= 10 ? i - 11 : i - 1));
        const int nleft = (d + 127) >> 7;              // producers needed (<=4)
        const int nright = (dprev + 127) >> 7;         // anti-dep readers (<=4; 0 at i=0)

        // ---- wait for neighbor progress (relaxed polls of LLC; no fences)
        if (w == 0) {
            int nb = -1;
            if (l < 4) { int k = l + 1; if (k <= nleft) nb = blk - k; }
            else if (l < 8) { int k = l - 3; if (k <= nright) nb = blk + k; }
            if (nb >= 0 && nb < NBLOCKS) {
                unsigned tgt = (unsigned)(i + 1);
                while (__hip_atomic_load(&flags[nb << 5], __ATOMIC_RELAXED,
                                         __HIP_MEMORY_SCOPE_AGENT) < tgt)
                    __builtin_amdgcn_s_sleep(4);
            }
        }
        __syncthreads();

        const ushort_t* PW = pbf + i * PBF_PER_LAYER;
        const float* bfb = bf_all + i * 64;
        const float* bgb = bg_all + i * 64;
        const float* brb = br_all + i * 64;
        const float* bsb = bs_all + i * 64;

        const int rLw = max(tauW - d, 0);

        // ---- batch-issue gate loads (8) THEN residual loads (4), all sc1.
        // "=&v" early-clobber mandatory (R5 crash lesson).
        f32x4 gA, gB, gC, gD, oA, oB, oC, oD;
        {
            const float* pL = Hin + rLw * 64 + quad * 8;
            const float* pO = Hin + tauW * 64 + quad * 8;
            asm volatile(
                "global_load_dwordx4 %0, %8, off sc1\n\t"
                "global_load_dwordx4 %1, %8, off offset:16 sc1\n\t"
                "global_load_dwordx4 %2, %8, off offset:128 sc1\n\t"
                "global_load_dwordx4 %3, %8, off offset:144 sc1\n\t"
                "global_load_dwordx4 %4, %9, off sc1\n\t"
                "global_load_dwordx4 %5, %9, off offset:16 sc1\n\t"
                "global_load_dwordx4 %6, %9, off offset:128 sc1\n\t"
                "global_load_dwordx4 %7, %9, off offset:144 sc1"
                : "=&v"(gA), "=&v"(gB), "=&v"(gC), "=&v"(gD),
                  "=&v"(oA), "=&v"(oB), "=&v"(oC), "=&v"(oD)
                : "v"(pL), "v"(pO) : "memory");
        }
        f32x4 h0, h1, h2, h3;
        {
            const float* hb = Hin + tauW * 64 + quad * 4;
            asm volatile(
                "global_load_dwordx4 %0, %4, off sc1\n\t"
                "global_load_dwordx4 %1, %4, off offset:64 sc1\n\t"
                "global_load_dwordx4 %2, %4, off offset:128 sc1\n\t"
                "global_load_dwordx4 %3, %4, off offset:192 sc1"
                : "=&v"(h0), "=&v"(h1), "=&v"(h2), "=&v"(h3)
                : "v"(hb) : "memory");
        }
        asm volatile("s_waitcnt vmcnt(4)" ::: "memory");   // gates done; residual in flight
        __builtin_amdgcn_sched_barrier(0);                 // rule #18

        bf16x8 bl[4];
        bl[0] = cvt8(gA, gB);
        bl[1] = cvt8(gC, gD);
        bl[2] = cvt8(oA, oB);
        bl[3] = cvt8(oC, oD);

        // ---- gates GEMM, biases folded into accumulator init
        f32x4 acc[8];
        #pragma unroll
        for (int mt = 0; mt < 4; ++mt) {
            acc[mt]     = *(const f32x4*)(bfb + mt * 16 + quad * 4);
            acc[mt + 4] = *(const f32x4*)(bgb + mt * 16 + quad * 4);
        }
        #pragma unroll
        for (int ks = 0; ks < 4; ++ks) {
            #pragma unroll
            for (int mt = 0; mt < 8; ++mt) {
                BF8 af; af.u4 = *(const uint4v*)(PW + (((mt << 2) + ks) * 64 + l) * 8);
                acc[mt] = __builtin_amdgcn_mfma_f32_16x16x32_bf16(af.v, bl[ks], acc[mt], 0, 0, 0);
            }
        }

        // ---- z = tanh(f)*sigmoid(g) -> ZB
        #pragma unroll
        for (int mt = 0; mt < 4; ++mt) {
            u64_t pk = 0;
            #pragma unroll
            for (int r = 0; r < 4; ++r) {
                float f = acc[mt][r];
                float g = acc[mt + 4][r];
                float e2 = __expf(2.0f * f);
                float th = 1.0f - 2.0f / (e2 + 1.0f);
                float sg = 1.0f / (1.0f + __expf(-g));
                pk |= (u64_t)f2bf(th * sg) << (r * 16);
            }
            *(u64_t*)(ZB + nloc * 72 + mt * 16 + quad * 4) = pk;
        }
        __syncthreads();   // orders ZB stores before 128-bit ZB reads (TBAA lesson)

        // ---- res/skip GEMM, biases in acc init
        f32x4 acc2[8];
        #pragma unroll
        for (int mt = 0; mt < 4; ++mt) {
            acc2[mt]     = *(const f32x4*)(brb + mt * 16 + quad * 4);
            acc2[mt + 4] = *(const f32x4*)(bsb + mt * 16 + quad * 4);
        }
        const ushort_t* PRS = PW + 16384;
        #pragma unroll
        for (int ks = 0; ks < 2; ++ks) {
            BF8 t; t.u4 = *(const uint4v*)(ZB + nloc * 72 + ks * 32 + quad * 8);
            #pragma unroll
            for (int mt = 0; mt < 8; ++mt) {
                BF8 af; af.u4 = *(const uint4v*)(PRS + (((mt << 1) + ks) * 64 + l) * 8);
                acc2[mt] = __builtin_amdgcn_mfma_f32_16x16x32_bf16(af.v, t.v, acc2[mt], 0, 0, 0);
            }
        }

        // ---- epilogue: Hout = res + right (sc1); skip accumulates in registers
        asm volatile("s_waitcnt vmcnt(0)" ::: "memory");   // residual loads done
        __builtin_amdgcn_sched_barrier(0);
        {
            f32x4 hv[4] = { h0, h1, h2, h3 };
            f32x4 ov[4];
            #pragma unroll
            for (int mt = 0; mt < 4; ++mt) {
                #pragma unroll
                for (int r = 0; r < 4; ++r) {
                    ov[mt][r] = acc2[mt][r] + hv[mt][r];
                    skip_acc[mt][r] += acc2[mt + 4][r];
                }
            }
            if (i < NLAYERS - 1) {
                float* ho = Hout + tauW * 64 + quad * 4;
                asm volatile(
                    "global_store_dwordx4 %0, %1, off sc1\n\t"
                    "global_store_dwordx4 %0, %2, off offset:64 sc1\n\t"
                    "global_store_dwordx4 %0, %3, off offset:128 sc1\n\t"
                    "global_store_dwordx4 %0, %4, off offset:192 sc1"
                    :: "v"(ho), "v"(ov[0]), "v"(ov[1]), "v"(ov[2]), "v"(ov[3])
                    : "memory");
            }
        }

        // ---- publish layer completion (relaxed; sc1 data at LLC after waitcnt)
        asm volatile("s_waitcnt vmcnt(0)" ::: "memory");
        __syncthreads();
        if (i < NLAYERS - 1 && tid == 0)
            __hip_atomic_store(&flags[blk << 5], (unsigned)(i + 2), __ATOMIC_RELAXED,
                               __HIP_MEMORY_SCOPE_AGENT);

        float* t = Hin; Hin = Hout; Hout = t;
    }

    // ---- output head (block-local; skip is in registers)
    // Phase A: Y0 = lrelu_alpha0(skip) -> ZB (row nloc, wave-local)
    #pragma unroll
    for (int mt = 0; mt < 4; ++mt) {
        f32x4 a = *(const f32x4*)(alpha + mt * 16 + quad * 4);
        u64_t pk = 0;
        #pragma unroll
        for (int r = 0; r < 4; ++r) {
            float x = skip_acc[mt][r];
            x = x > 0.0f ? x : a[r] * x;
            pk |= (u64_t)f2bf(x) << (r * 16);
        }
        *(u64_t*)(ZB + nloc * 72 + mt * 16 + quad * 4) = pk;
    }
    __syncthreads();

    const ushort_t* PW0 = pbf + PBF_LAYERS;
    const ushort_t* PW1 = PW0 + 4096;

    // W0 GEMM (64x64), bias in acc init
    f32x4 acc0[4];
    #pragma unroll
    for (int mt = 0; mt < 4; ++mt) acc0[mt] = *(const f32x4*)(b_out0 + mt * 16 + quad * 4);
    #pragma unroll
    for (int ks = 0; ks < 2; ++ks) {
        BF8 t; t.u4 = *(const uint4v*)(ZB + nloc * 72 + ks * 32 + quad * 8);
        #pragma unroll
        for (int mt = 0; mt < 4; ++mt) {
            BF8 af; af.u4 = *(const uint4v*)(PW0 + (((mt << 1) + ks) * 64 + l) * 8);
            acc0[mt] = __builtin_amdgcn_mfma_f32_16x16x32_bf16(af.v, t.v, acc0[mt], 0, 0, 0);
        }
    }

    // lrelu_alpha1 -> YB (row nloc, wave-local)
    #pragma unroll
    for (int mt = 0; mt < 4; ++mt) {
        f32x4 a = *(const f32x4*)(alpha + 64 + mt * 16 + quad * 4);
        u64_t pk = 0;
        #pragma unroll
        for (int r = 0; r < 4; ++r) {
            float x = acc0[mt][r];
            x = x > 0.0f ? x : a[r] * x;
            pk |= (u64_t)f2bf(x) << (r * 16);
        }
        *(u64_t*)(YB + nloc * 72 + mt * 16 + quad * 4) = pk;
    }
    __syncthreads();

    // W1 GEMM (256x64), bias in acc init
    f32x4 acc1[16];
    #pragma unroll
    for (int mt = 0; mt < 16; ++mt) acc1[mt] = *(const f32x4*)(b_out1 + mt * 16 + quad * 4);
    #pragma unroll
    for (int ks = 0; ks < 2; ++ks) {
        BF8 t; t.u4 = *(const uint4v*)(YB + nloc * 72 + ks * 32 + quad * 8);
        #pragma unroll
        for (int mt = 0; mt < 16; ++mt) {
            BF8 af; af.u4 = *(const uint4v*)(PW1 + (((mt << 1) + ks) * 64 + l) * 8);
            acc1[mt] = __builtin_amdgcn_mfma_f32_16x16x32_bf16(af.v, t.v, acc1[mt], 0, 0, 0);
        }
    }

    int u = tau0 + nloc - OUT_START;
    if (u >= 0) {
        #pragma unroll
        for (int mt = 0; mt < 16; ++mt)
            #pragma unroll
            for (int r = 0; r < 4; ++r)
                out[(mt * 16 + quad * 4 + r) * OUT_W + u] = acc1[mt][r];
    }
}

// ---------------------------------------------------------------- launch
extern "C" void kernel_launch(void* const* d_in, const int* in_sizes, int n_in,
                              void* d_out, int out_size, void* d_ws, size_t ws_size,
                              hipStream_t stream)
{
    const float* input  = (const float*)d_in[0];
    const float* w0     = (const float*)d_in[1];
    const float* b0     = (const float*)d_in[2];
    const float* wf     = (const float*)d_in[3];
    const float* bf     = (const float*)d_in[4];
    const float* wg     = (const float*)d_in[5];
    const float* bg     = (const float*)d_in[6];
    const float* wr     = (const float*)d_in[7];
    const float* br     = (const float*)d_in[8];
    const float* wsk    = (const float*)d_in[9];
    const float* bs     = (const float*)d_in[10];
    const float* alpha  = (const float*)d_in[11];
    const float* w_out0 = (const float*)d_in[12];
    const float* b_out0 = (const float*)d_in[13];
    const float* w_out1 = (const float*)d_in[14];
    const float* b_out1 = (const float*)d_in[15];
    float* outp = (float*)d_out;

    float* wsbase = (float*)d_ws;
    ushort_t* pbf = (ushort_t*)wsbase;
    float* HA = wsbase + H0_OFF;
    float* HB = wsbase + H1_OFF;
    unsigned* flags = (unsigned*)(wsbase + FLAG_OFF);

    pack_mfma<<<PBF_TOTAL / 256, 256, 0, stream>>>(wf, wg, wr, wsk, w_out0, w_out1, pbf, flags);

    wavenet_fused<<<dim3(NBLOCKS), dim3(512), 0, stream>>>(
        input, w0, b0, pbf, bf, bg, br, bs, alpha, b_out0, b_out1,
        HA, HB, outp, flags);
}

// Round 9
// 461.153 us; speedup vs baseline: 1.3115x; 1.3115x over previous
//
#include <hip/hip_runtime.h>

typedef unsigned short ushort_t;
typedef unsigned long long u64_t;
typedef __attribute__((ext_vector_type(8))) __bf16 bf16x8;
typedef __attribute__((ext_vector_type(4))) float f32x4;
typedef __attribute__((ext_vector_type(4))) unsigned int uint4v;

#define T_TOTAL 65536
#define NLAYERS 20
#define OUT_START 2047
#define OUT_W 63489
#define NBLOCKS 512

// workspace layout (floats)
#define PBF_PER_LAYER 24576
#define PBF_LAYERS (NLAYERS * PBF_PER_LAYER)        // 491520 ushorts
#define PBF_TOTAL (PBF_LAYERS + 4096 + 16384)       // 512000 ushorts
#define HALO0_OFF 524288
#define HALO_FLOATS ((T_TOTAL * 64) / 2)            // bf16 halo buf = T*64 ushorts = 2,097,152 floats
#define HALO1_OFF (HALO0_OFF + HALO_FLOATS)
#define FLAG_OFF (HALO1_OFF + HALO_FLOATS)          // 512 flags, 128B apart

__device__ __forceinline__ ushort_t f2bf(float x) {
    union { float f; unsigned u; } c; c.f = x;
    unsigned u = c.u + 0x7FFFu + ((c.u >> 16) & 1u);   // RNE
    return (ushort_t)(u >> 16);
}

union BF8 { uint4v u4; bf16x8 v; };

__device__ __forceinline__ bf16x8 cvt8(f32x4 a, f32x4 b) {
    union { unsigned u[4]; bf16x8 v; } r;
    r.u[0] = (unsigned)f2bf(a[0]) | ((unsigned)f2bf(a[1]) << 16);
    r.u[1] = (unsigned)f2bf(a[2]) | ((unsigned)f2bf(a[3]) << 16);
    r.u[2] = (unsigned)f2bf(b[0]) | ((unsigned)f2bf(b[1]) << 16);
    r.u[3] = (unsigned)f2bf(b[2]) | ((unsigned)f2bf(b[3]) << 16);
    return r.v;
}

__device__ __forceinline__ u64_t pack4bf(f32x4 v) {
    return (u64_t)f2bf(v[0]) | ((u64_t)f2bf(v[1]) << 16) |
           ((u64_t)f2bf(v[2]) << 32) | ((u64_t)f2bf(v[3]) << 48);
}

// ---------------------------------------------------------------- pack ALL MFMA weights (bf16, A-fragment order)
__global__ __launch_bounds__(256) void pack_mfma(
    const float* __restrict__ wf, const float* __restrict__ wg,
    const float* __restrict__ wr, const float* __restrict__ wsk,
    const float* __restrict__ w0h, const float* __restrict__ w1h,
    ushort_t* __restrict__ out, unsigned* __restrict__ flags)
{
    int idx = blockIdx.x * 256 + threadIdx.x;
    if (idx < NBLOCKS) flags[idx << 5] = 0u;   // reset progress flags every launch (replay-safe)
    if (idx >= PBF_TOTAL) return;
    float v;
    if (idx < PBF_LAYERS) {
        int i = idx / PBF_PER_LAYER;
        int r = idx - i * PBF_PER_LAYER;
        if (r < 16384) {                  // gates A (128x128 = [f;g] x [left||right])
            int j = r & 7, l = (r >> 3) & 63, ks = (r >> 9) & 3, mt = r >> 11;
            int m = mt * 16 + (l & 15);
            int k = ks * 32 + ((l >> 4) << 3) + j;
            int o = m & 63, c = k & 63, half = k >> 6;
            const float* src = (m < 64) ? wf : wg;
            v = src[(((i * 64 + o) * 64 + c) << 1) + half];
        } else {                          // rs A (128x64 = [r;s] x c)
            int rr = r - 16384;
            int j = rr & 7, l = (rr >> 3) & 63, ks = (rr >> 9) & 1, mt = rr >> 10;
            int m = mt * 16 + (l & 15);
            int k = ks * 32 + ((l >> 4) << 3) + j;
            v = (m < 64) ? wr[(i * 64 + m) * 64 + k] : wsk[(i * 64 + (m - 64)) * 64 + k];
        }
    } else if (idx < PBF_LAYERS + 4096) { // W0 head (64x64)
        int rr = idx - PBF_LAYERS;
        int j = rr & 7, l = (rr >> 3) & 63, ks = (rr >> 9) & 1, mt = rr >> 10;
        int m = mt * 16 + (l & 15);
        int k = ks * 32 + ((l >> 4) << 3) + j;
        v = w0h[m * 64 + k];
    } else {                              // W1 head (256x64)
        int rr = idx - PBF_LAYERS - 4096;
        int j = rr & 7, l = (rr >> 3) & 63, ks = (rr >> 9) & 1, mt = rr >> 10;
        int m = mt * 16 + (l & 15);
        int k = ks * 32 + ((l >> 4) << 3) + j;
        v = w1h[m * 64 + k];
    }
    out[idx] = f2bf(v);
}

// ---------------------------------------------------------------- fused persistent kernel
// R8/R9: R6/R7 both plateaued at ~1.5 TB/s on the sc1/LLC path (hbm_gbps
// identical across configs) -> BW-bound on uncached H traffic. Fix: the 128x64
// fp32 H tile lives in LDS (own rows + residual never leave the block); only
// the min(d_next,128)-row halo is exchanged through the LLC, AS BF16
// (numerically identical: that operand is RNE-converted to bf16 before MFMA
// anyway). Traffic: 786 MB -> ~200 MB. Flag protocol unchanged from R6.
// LDS HT uses XOR-swizzled 16B granules (granule g of row r at g^(r&7)):
// conflict-free ds_read_b128 for both col-slices and 16-row column reads.
// (R8 bench was an infra failure — container never came up; kernel re-audited
// clean: halo alternation/coverage, flag waits, bounds, swizzle consistency.)
__global__ __launch_bounds__(512, 4) void wavenet_fused(
    const float* __restrict__ in, const float* __restrict__ w0v, const float* __restrict__ b0v,
    const ushort_t* __restrict__ pbf,
    const float* __restrict__ bf_all, const float* __restrict__ bg_all,
    const float* __restrict__ br_all, const float* __restrict__ bs_all,
    const float* __restrict__ alpha, const float* __restrict__ b_out0,
    const float* __restrict__ b_out1,
    ushort_t* __restrict__ HALO0, ushort_t* __restrict__ HALO1,
    float* __restrict__ out, unsigned* flags)
{
    __shared__ alignas(16) float HT[128 * 64];      // 32 KB fp32 tile (swizzled granules)
    __shared__ alignas(16) ushort_t ZB[128 * 72];   // 18 KB z staging (head reuses it)

    const int tid = threadIdx.x;
    const int l = tid & 63, w = tid >> 6;          // 8 waves
    const int l15 = l & 15, quad = l >> 4;
    const int bid = (int)blockIdx.x;
    const int blk = (bid & 7) * 64 + (bid >> 3);   // XCD-chunked swizzle
    const int tau0 = blk * 128;
    const int tauW = tau0 + w * 16 + l15;          // this wave's 16-row tile
    const int nloc = w * 16 + l15;                 // local row (0..127)

// swizzled granule address: 16B granule g of row r lives at g^(r&7)
#define HTA(r, g) ((f32x4*)(HT + (r) * 64 + ((((g) ^ ((r) & 7))) << 2)))

    // ---- init h0 into LDS; publish last row (d_0=1 halo) as bf16 -> HALO0
    #pragma unroll
    for (int it = 0; it < 4; ++it) {
        int idx = (it << 9) + tid;           // 0..2047 granule-slots
        int trow = idx >> 4, cg = idx & 15;
        float x = in[tau0 + trow];
        f32x4 wv = *(const f32x4*)(w0v + cg * 4);
        f32x4 bv = *(const f32x4*)(b0v + cg * 4);
        f32x4 v;
        #pragma unroll
        for (int r = 0; r < 4; ++r) v[r] = fmaf(wv[r], x, bv[r]);
        *HTA(trow, cg) = v;
        if (trow == 127) {
            u64_t pk = pack4bf(v);
            ushort_t* dst = HALO0 + (tau0 + 127) * 64 + cg * 4;
            asm volatile("global_store_dwordx2 %0, %1, off sc1" :: "v"(dst), "v"(pk) : "memory");
        }
    }
    asm volatile("s_waitcnt vmcnt(0)" ::: "memory");
    __syncthreads();
    if (tid == 0)
        __hip_atomic_store(&flags[blk << 5], 1u, __ATOMIC_RELAXED, __HIP_MEMORY_SCOPE_AGENT);

    f32x4 skip_acc[4];
    #pragma unroll
    for (int mt = 0; mt < 4; ++mt) skip_acc[mt] = (f32x4){0.0f, 0.0f, 0.0f, 0.0f};

    #pragma unroll 1
    for (int i = 0; i < NLAYERS; ++i) {
        const int d = 1 << (i >= 10 ? i - 10 : i);
        const int dprev = (i == 0) ? 0 : (1 << ((i - 1) >= 10 ? i - 11 : i - 1));
        const int ip1 = i + 1;
        const int dnext = (ip1 < NLAYERS) ? (1 << (ip1 >= 10 ? ip1 - 10 : ip1)) : 0;
        const int hn = dnext > 128 ? 128 : dnext;      // rows to publish for next layer
        const int nleft = (d + 127) >> 7;              // producers needed (<=4)
        const int nright = (dprev + 127) >> 7;         // anti-dep readers (<=4; 0 at i=0)
        const ushort_t* haloIn = (i & 1) ? HALO1 : HALO0;
        ushort_t* haloOut = (i & 1) ? HALO0 : HALO1;

        // ---- wait for neighbor progress (relaxed polls of LLC; no fences)
        if (w == 0) {
            int nb = -1;
            if (l < 4) { int k = l + 1; if (k <= nleft) nb = blk - k; }
            else if (l < 8) { int k = l - 3; if (k <= nright) nb = blk + k; }
            if (nb >= 0 && nb < NBLOCKS) {
                unsigned tgt = (unsigned)(i + 1);
                while (__hip_atomic_load(&flags[nb << 5], __ATOMIC_RELAXED,
                                         __HIP_MEMORY_SCOPE_AGENT) < tgt)
                    __builtin_amdgcn_s_sleep(2);
            }
        }
        __syncthreads();

        const ushort_t* PW = pbf + i * PBF_PER_LAYER;
        const float* bfb = bf_all + i * 64;
        const float* bgb = bg_all + i * 64;
        const float* brb = br_all + i * 64;
        const float* bsb = bs_all + i * 64;

        // ---- gates B operands: left from halo (bf16, direct) or LDS; own from LDS
        int grow = tauW - d; if (grow < 0) grow = 0;
        bf16x8 bl[4];
        if (grow < tau0) {
            const ushort_t* hp = haloIn + grow * 64 + quad * 8;
            asm volatile(
                "global_load_dwordx4 %0, %2, off sc1\n\t"
                "global_load_dwordx4 %1, %2, off offset:64 sc1"
                : "=&v"(bl[0]), "=&v"(bl[1]) : "v"(hp) : "memory");
        } else {
            int rl = grow - tau0;
            bl[0] = cvt8(*HTA(rl, 2 * quad), *HTA(rl, 2 * quad + 1));
            bl[1] = cvt8(*HTA(rl, 2 * quad + 8), *HTA(rl, 2 * quad + 9));
        }
        bl[2] = cvt8(*HTA(nloc, 2 * quad), *HTA(nloc, 2 * quad + 1));
        bl[3] = cvt8(*HTA(nloc, 2 * quad + 8), *HTA(nloc, 2 * quad + 9));
        asm volatile("s_waitcnt vmcnt(0)" ::: "memory");
        __builtin_amdgcn_sched_barrier(0);             // rule #18

        // ---- gates GEMM, biases folded into accumulator init
        f32x4 acc[8];
        #pragma unroll
        for (int mt = 0; mt < 4; ++mt) {
            acc[mt]     = *(const f32x4*)(bfb + mt * 16 + quad * 4);
            acc[mt + 4] = *(const f32x4*)(bgb + mt * 16 + quad * 4);
        }
        #pragma unroll
        for (int ks = 0; ks < 4; ++ks) {
            #pragma unroll
            for (int mt = 0; mt < 8; ++mt) {
                BF8 af; af.u4 = *(const uint4v*)(PW + (((mt << 2) + ks) * 64 + l) * 8);
                acc[mt] = __builtin_amdgcn_mfma_f32_16x16x32_bf16(af.v, bl[ks], acc[mt], 0, 0, 0);
            }
        }

        // ---- z = tanh(f)*sigmoid(g) -> ZB
        #pragma unroll
        for (int mt = 0; mt < 4; ++mt) {
            u64_t pk = 0;
            #pragma unroll
            for (int r = 0; r < 4; ++r) {
                float f = acc[mt][r];
                float g = acc[mt + 4][r];
                float e2 = __expf(2.0f * f);
                float th = 1.0f - 2.0f / (e2 + 1.0f);
                float sg = 1.0f / (1.0f + __expf(-g));
                pk |= (u64_t)f2bf(th * sg) << (r * 16);
            }
            *(u64_t*)(ZB + nloc * 72 + mt * 16 + quad * 4) = pk;
        }
        __syncthreads();   // orders ZB stores before reads AND gates HT reads before epilogue HT writes

        // ---- res/skip GEMM, biases in acc init
        f32x4 acc2[8];
        #pragma unroll
        for (int mt = 0; mt < 4; ++mt) {
            acc2[mt]     = *(const f32x4*)(brb + mt * 16 + quad * 4);
            acc2[mt + 4] = *(const f32x4*)(bsb + mt * 16 + quad * 4);
        }
        const ushort_t* PRS = PW + 16384;
        #pragma unroll
        for (int ks = 0; ks < 2; ++ks) {
            BF8 t; t.u4 = *(const uint4v*)(ZB + nloc * 72 + ks * 32 + quad * 8);
            #pragma unroll
            for (int mt = 0; mt < 8; ++mt) {
                BF8 af; af.u4 = *(const uint4v*)(PRS + (((mt << 1) + ks) * 64 + l) * 8);
                acc2[mt] = __builtin_amdgcn_mfma_f32_16x16x32_bf16(af.v, t.v, acc2[mt], 0, 0, 0);
            }
        }

        // ---- epilogue: Hout = res + right (LDS in-place); publish bf16 halo rows
        {
            f32x4 hv[4], ov[4];
            #pragma unroll
            for (int mt = 0; mt < 4; ++mt) hv[mt] = *HTA(nloc, quad + 4 * mt);
            #pragma unroll
            for (int mt = 0; mt < 4; ++mt) {
                #pragma unroll
                for (int r = 0; r < 4; ++r) {
                    ov[mt][r] = acc2[mt][r] + hv[mt][r];
                    skip_acc[mt][r] += acc2[mt + 4][r];
                }
            }
            if (i < NLAYERS - 1) {
                #pragma unroll
                for (int mt = 0; mt < 4; ++mt) *HTA(nloc, quad + 4 * mt) = ov[mt];
                if (nloc >= 128 - hn) {
                    ushort_t* hbase = haloOut + (tau0 + nloc) * 64 + quad * 4;
                    #pragma unroll
                    for (int mt = 0; mt < 4; ++mt) {
                        u64_t pk = pack4bf(ov[mt]);
                        ushort_t* dst = hbase + mt * 16;
                        asm volatile("global_store_dwordx2 %0, %1, off sc1"
                                     :: "v"(dst), "v"(pk) : "memory");
                    }
                }
            }
        }

        // ---- publish layer completion (relaxed; halo at LLC after waitcnt)
        asm volatile("s_waitcnt vmcnt(0)" ::: "memory");
        __syncthreads();   // also orders epilogue HT writes before next layer's HT reads
        if (i < NLAYERS - 1 && tid == 0)
            __hip_atomic_store(&flags[blk << 5], (unsigned)(i + 2), __ATOMIC_RELAXED,
                               __HIP_MEMORY_SCOPE_AGENT);
    }

    // ---- output head (block-local; skip in registers; ZB reused for Y0 then X1)
    #pragma unroll
    for (int mt = 0; mt < 4; ++mt) {
        f32x4 a = *(const f32x4*)(alpha + mt * 16 + quad * 4);
        u64_t pk = 0;
        #pragma unroll
        for (int r = 0; r < 4; ++r) {
            float x = skip_acc[mt][r];
            x = x > 0.0f ? x : a[r] * x;
            pk |= (u64_t)f2bf(x) << (r * 16);
        }
        *(u64_t*)(ZB + nloc * 72 + mt * 16 + quad * 4) = pk;
    }
    __syncthreads();

    const ushort_t* PW0 = pbf + PBF_LAYERS;
    const ushort_t* PW1 = PW0 + 4096;

    // W0 GEMM (64x64), bias in acc init
    f32x4 acc0[4];
    #pragma unroll
    for (int mt = 0; mt < 4; ++mt) acc0[mt] = *(const f32x4*)(b_out0 + mt * 16 + quad * 4);
    #pragma unroll
    for (int ks = 0; ks < 2; ++ks) {
        BF8 t; t.u4 = *(const uint4v*)(ZB + nloc * 72 + ks * 32 + quad * 8);
        #pragma unroll
        for (int mt = 0; mt < 4; ++mt) {
            BF8 af; af.u4 = *(const uint4v*)(PW0 + (((mt << 1) + ks) * 64 + l) * 8);
            acc0[mt] = __builtin_amdgcn_mfma_f32_16x16x32_bf16(af.v, t.v, acc0[mt], 0, 0, 0);
        }
    }
    __syncthreads();

    // lrelu_alpha1 -> X1 back into ZB (wave-local rows)
    #pragma unroll
    for (int mt = 0; mt < 4; ++mt) {
        f32x4 a = *(const f32x4*)(alpha + 64 + mt * 16 + quad * 4);
        u64_t pk = 0;
        #pragma unroll
        for (int r = 0; r < 4; ++r) {
            float x = acc0[mt][r];
            x = x > 0.0f ? x : a[r] * x;
            pk |= (u64_t)f2bf(x) << (r * 16);
        }
        *(u64_t*)(ZB + nloc * 72 + mt * 16 + quad * 4) = pk;
    }
    __syncthreads();

    // W1 GEMM (256x64), bias in acc init
    f32x4 acc1[16];
    #pragma unroll
    for (int mt = 0; mt < 16; ++mt) acc1[mt] = *(const f32x4*)(b_out1 + mt * 16 + quad * 4);
    #pragma unroll
    for (int ks = 0; ks < 2; ++ks) {
        BF8 t; t.u4 = *(const uint4v*)(ZB + nloc * 72 + ks * 32 + quad * 8);
        #pragma unroll
        for (int mt = 0; mt < 16; ++mt) {
            BF8 af; af.u4 = *(const uint4v*)(PW1 + (((mt << 1) + ks) * 64 + l) * 8);
            acc1[mt] = __builtin_amdgcn_mfma_f32_16x16x32_bf16(af.v, t.v, acc1[mt], 0, 0, 0);
        }
    }

    int u = tau0 + nloc - OUT_START;
    if (u >= 0) {
        #pragma unroll
        for (int mt = 0; mt < 16; ++mt)
            #pragma unroll
            for (int r = 0; r < 4; ++r)
                out[(mt * 16 + quad * 4 + r) * OUT_W + u] = acc1[mt][r];
    }
#undef HTA
}

// ---------------------------------------------------------------- launch
extern "C" void kernel_launch(void* const* d_in, const int* in_sizes, int n_in,
                              void* d_out, int out_size, void* d_ws, size_t ws_size,
                              hipStream_t stream)
{
    const float* input  = (const float*)d_in[0];
    const float* w0     = (const float*)d_in[1];
    const float* b0     = (const float*)d_in[2];
    const float* wf     = (const float*)d_in[3];
    const float* bf     = (const float*)d_in[4];
    const float* wg     = (const float*)d_in[5];
    const float* bg     = (const float*)d_in[6];
    const float* wr     = (const float*)d_in[7];
    const float* br     = (const float*)d_in[8];
    const float* wsk    = (const float*)d_in[9];
    const float* bs     = (const float*)d_in[10];
    const float* alpha  = (const float*)d_in[11];
    const float* w_out0 = (const float*)d_in[12];
    const float* b_out0 = (const float*)d_in[13];
    const float* w_out1 = (const float*)d_in[14];
    const float* b_out1 = (const float*)d_in[15];
    float* outp = (float*)d_out;

    float* wsbase = (float*)d_ws;
    ushort_t* pbf = (ushort_t*)wsbase;
    ushort_t* HALO0 = (ushort_t*)(wsbase + HALO0_OFF);
    ushort_t* HALO1 = (ushort_t*)(wsbase + HALO1_OFF);
    unsigned* flags = (unsigned*)(wsbase + FLAG_OFF);

    pack_mfma<<<PBF_TOTAL / 256, 256, 0, stream>>>(wf, wg, wr, wsk, w_out0, w_out1, pbf, flags);

    wavenet_fused<<<dim3(NBLOCKS), dim3(512), 0, stream>>>(
        input, w0, b0, pbf, bf, bg, br, bs, alpha, b_out0, b_out1,
        HALO0, HALO1, outp, flags);
}

// Round 10
// 459.518 us; speedup vs baseline: 1.3162x; 1.0036x over previous
//
#include <hip/hip_runtime.h>

typedef unsigned short ushort_t;
typedef unsigned long long u64_t;
typedef __attribute__((ext_vector_type(8))) __bf16 bf16x8;
typedef __attribute__((ext_vector_type(4))) __bf16 bf16x4;
typedef __attribute__((ext_vector_type(4))) float f32x4;
typedef __attribute__((ext_vector_type(4))) unsigned int uint4v;

#define T_TOTAL 65536
#define NLAYERS 20
#define OUT_START 2047
#define OUT_W 63489
#define NBLOCKS 512

// workspace layout (floats)
#define PBF_PER_LAYER 24576
#define PBF_LAYERS (NLAYERS * PBF_PER_LAYER)        // 491520 ushorts
#define PBF_TOTAL (PBF_LAYERS + 4096 + 16384)       // 512000 ushorts
#define HALO0_OFF 524288
#define HALO_FLOATS ((T_TOTAL * 64) / 2)            // bf16 halo buf = T*64 ushorts
#define HALO1_OFF (HALO0_OFF + HALO_FLOATS)
#define FLAG_OFF (HALO1_OFF + HALO_FLOATS)          // 512 flags, 128B apart

__device__ __forceinline__ ushort_t f2bf(float x) {
    union { float f; unsigned u; } c; c.f = x;
    unsigned u = c.u + 0x7FFFu + ((c.u >> 16) & 1u);   // RNE
    return (ushort_t)(u >> 16);
}

union BF8 { uint4v u4; bf16x8 v; };

// HW bf16 pack (compiler emits v_cvt_pk_bf16_f32, RNE — m240: faster than bit math)
__device__ __forceinline__ u64_t pk4(f32x4 v) {
    union { bf16x4 b; u64_t u; } r;
    r.b[0] = (__bf16)v[0]; r.b[1] = (__bf16)v[1];
    r.b[2] = (__bf16)v[2]; r.b[3] = (__bf16)v[3];
    return r.u;
}

// ---------------------------------------------------------------- pack ALL MFMA weights (bf16, A-fragment order)
__global__ __launch_bounds__(256) void pack_mfma(
    const float* __restrict__ wf, const float* __restrict__ wg,
    const float* __restrict__ wr, const float* __restrict__ wsk,
    const float* __restrict__ w0h, const float* __restrict__ w1h,
    ushort_t* __restrict__ out, unsigned* __restrict__ flags)
{
    int idx = blockIdx.x * 256 + threadIdx.x;
    if (idx < NBLOCKS) flags[idx << 5] = 0u;   // reset progress flags every launch (replay-safe)
    if (idx >= PBF_TOTAL) return;
    float v;
    if (idx < PBF_LAYERS) {
        int i = idx / PBF_PER_LAYER;
        int r = idx - i * PBF_PER_LAYER;
        if (r < 16384) {                  // gates A (128x128 = [f;g] x [left||right])
            int j = r & 7, l = (r >> 3) & 63, ks = (r >> 9) & 3, mt = r >> 11;
            int m = mt * 16 + (l & 15);
            int k = ks * 32 + ((l >> 4) << 3) + j;
            int o = m & 63, c = k & 63, half = k >> 6;
            const float* src = (m < 64) ? wf : wg;
            v = src[(((i * 64 + o) * 64 + c) << 1) + half];
        } else {                          // rs A (128x64 = [r;s] x c)
            int rr = r - 16384;
            int j = rr & 7, l = (rr >> 3) & 63, ks = (rr >> 9) & 1, mt = rr >> 10;
            int m = mt * 16 + (l & 15);
            int k = ks * 32 + ((l >> 4) << 3) + j;
            v = (m < 64) ? wr[(i * 64 + m) * 64 + k] : wsk[(i * 64 + (m - 64)) * 64 + k];
        }
    } else if (idx < PBF_LAYERS + 4096) { // W0 head (64x64)
        int rr = idx - PBF_LAYERS;
        int j = rr & 7, l = (rr >> 3) & 63, ks = (rr >> 9) & 1, mt = rr >> 10;
        int m = mt * 16 + (l & 15);
        int k = ks * 32 + ((l >> 4) << 3) + j;
        v = w0h[m * 64 + k];
    } else {                              // W1 head (256x64)
        int rr = idx - PBF_LAYERS - 4096;
        int j = rr & 7, l = (rr >> 3) & 63, ks = (rr >> 9) & 1, mt = rr >> 10;
        int m = mt * 16 + (l & 15);
        int k = ks * 32 + ((l >> 4) << 3) + j;
        v = w1h[m * 64 + k];
    }
    out[idx] = f2bf(v);
}

// ---------------------------------------------------------------- fused persistent kernel
// R10 (on R9's halo design, fused 382us, VALUBusy 31% = top pipe):
//  - H stored as BF16 in LDS (double-buffered 2x16KB): gate operands read
//    pre-converted -> kills all 4 cvt8/layer. Numerics identical (same RNE,
//    producer-side).
//  - fp32 residual lives in registers hreg[4] (each thread's residual channels
//    == its acc2 fragment channels): fp32 adds bit-identical to R9.
//  - HT double-buffer removes the mid-layer barrier (gates read HT[cur],
//    epilogue writes HT[nxt]); ZB is wave-private rows -> lgkmcnt(0)+clobber
//    instead of barriers. 2 barriers/layer (post-poll, pre-flag).
//  - v_rcp_f32 for activation divisions; HW bf16 casts for packing.
// Halo protocol / flags / sc1 exchange unchanged from R9 (proven).
__global__ __launch_bounds__(512, 4) void wavenet_fused(
    const float* __restrict__ in, const float* __restrict__ w0v, const float* __restrict__ b0v,
    const ushort_t* __restrict__ pbf,
    const float* __restrict__ bf_all, const float* __restrict__ bg_all,
    const float* __restrict__ br_all, const float* __restrict__ bs_all,
    const float* __restrict__ alpha, const float* __restrict__ b_out0,
    const float* __restrict__ b_out1,
    ushort_t* __restrict__ HALO0, ushort_t* __restrict__ HALO1,
    float* __restrict__ out, unsigned* flags)
{
    __shared__ alignas(16) ushort_t HT[2 * 128 * 64];   // 32 KB bf16 H, double-buffered
    __shared__ alignas(16) ushort_t ZB[128 * 72];       // 18 KB z staging (head reuses)

    const int tid = threadIdx.x;
    const int l = tid & 63, w = tid >> 6;          // 8 waves
    const int l15 = l & 15, quad = l >> 4;
    const int bid = (int)blockIdx.x;
    const int blk = (bid & 7) * 64 + (bid >> 3);   // XCD-chunked swizzle
    const int tau0 = blk * 128;
    const int tauW = tau0 + w * 16 + l15;          // this wave's 16-row tile
    const int nloc = w * 16 + l15;                 // local row (0..127)

// 16B bf16 granule g (0..7) of row r in buffer c, XOR-swizzled by row
#define HTP(c, r, g) ((const uint4v*)((char*)HT + ((c) << 14) + ((r) << 7) + ((((g) ^ ((r) & 7))) << 4)))
// u64 write slot for ch chunk mt*16+quad*4 of row r in buffer c
#define HTW(c, r, mt, q) ((u64_t*)((char*)HT + ((c) << 14) + ((r) << 7) + ((((2 * (mt) + ((q) >> 1)) ^ ((r) & 7))) << 4) + (((q) & 1) << 3)))

    // ---- init: thread owns row nloc, ch chunks mt*16+quad*4; fp32 in hreg,
    //      bf16 into HT[0]; row 127 published to HALO0 (d_0 = 1)
    f32x4 hreg[4];
    {
        float x = in[tau0 + nloc];
        #pragma unroll
        for (int mt = 0; mt < 4; ++mt) {
            int c0 = mt * 16 + quad * 4;
            f32x4 wv = *(const f32x4*)(w0v + c0);
            f32x4 bv = *(const f32x4*)(b0v + c0);
            #pragma unroll
            for (int r = 0; r < 4; ++r) hreg[mt][r] = fmaf(wv[r], x, bv[r]);
            u64_t pk = pk4(hreg[mt]);
            *HTW(0, nloc, mt, quad) = pk;
            if (nloc == 127) {
                ushort_t* dst = HALO0 + (tau0 + 127) * 64 + c0;
                asm volatile("global_store_dwordx2 %0, %1, off sc1" :: "v"(dst), "v"(pk) : "memory");
            }
        }
    }
    asm volatile("s_waitcnt vmcnt(0)" ::: "memory");
    __syncthreads();
    if (tid == 0)
        __hip_atomic_store(&flags[blk << 5], 1u, __ATOMIC_RELAXED, __HIP_MEMORY_SCOPE_AGENT);

    f32x4 skip_acc[4];
    #pragma unroll
    for (int mt = 0; mt < 4; ++mt) skip_acc[mt] = (f32x4){0.0f, 0.0f, 0.0f, 0.0f};

    #pragma unroll 1
    for (int i = 0; i < NLAYERS; ++i) {
        const int cur = i & 1, nxt = cur ^ 1;
        const int d = 1 << (i >= 10 ? i - 10 : i);
        const int dprev = (i == 0) ? 0 : (1 << ((i - 1) >= 10 ? i - 11 : i - 1));
        const int ip1 = i + 1;
        const int dnext = (ip1 < NLAYERS) ? (1 << (ip1 >= 10 ? ip1 - 10 : ip1)) : 0;
        const int hn = dnext > 128 ? 128 : dnext;      // rows to publish for next layer
        const int nleft = (d + 127) >> 7;              // producers needed (<=4)
        const int nright = (dprev + 127) >> 7;         // anti-dep readers (<=4; 0 at i=0)
        const ushort_t* haloIn = cur ? HALO1 : HALO0;
        ushort_t* haloOut = cur ? HALO0 : HALO1;

        // ---- wait for neighbor progress (relaxed polls of LLC; no fences)
        if (w == 0) {
            int nb = -1;
            if (l < 4) { int k = l + 1; if (k <= nleft) nb = blk - k; }
            else if (l < 8) { int k = l - 3; if (k <= nright) nb = blk + k; }
            if (nb >= 0 && nb < NBLOCKS) {
                unsigned tgt = (unsigned)(i + 1);
                while (__hip_atomic_load(&flags[nb << 5], __ATOMIC_RELAXED,
                                         __HIP_MEMORY_SCOPE_AGENT) < tgt)
                    __builtin_amdgcn_s_sleep(2);
            }
        }
        __syncthreads();   // A: poll done; also orders prev-layer HT[cur] writes before reads

        const ushort_t* PW = pbf + i * PBF_PER_LAYER;
        const float* bfb = bf_all + i * 64;
        const float* bgb = bg_all + i * 64;
        const float* brb = br_all + i * 64;
        const float* bsb = bs_all + i * 64;

        // ---- gate B operands: left from halo (bf16 global) or HT[cur]; own from HT[cur]
        int grow = tauW - d; if (grow < 0) grow = 0;
        bf16x8 bl0, bl1, bl2, bl3;
        if (grow < tau0) {
            const ushort_t* hp = haloIn + grow * 64 + quad * 8;
            asm volatile(
                "global_load_dwordx4 %0, %2, off sc1\n\t"
                "global_load_dwordx4 %1, %2, off offset:64 sc1"
                : "=&v"(bl0), "=&v"(bl1) : "v"(hp) : "memory");
        } else {
            int rl = grow - tau0;
            BF8 a0, a1;
            a0.u4 = *HTP(cur, rl, quad);
            a1.u4 = *HTP(cur, rl, 4 + quad);
            bl0 = a0.v; bl1 = a1.v;
        }
        {
            BF8 b0, b1;
            b0.u4 = *HTP(cur, nloc, quad);
            b1.u4 = *HTP(cur, nloc, 4 + quad);
            bl2 = b0.v; bl3 = b1.v;
        }
        asm volatile("s_waitcnt vmcnt(0) lgkmcnt(0)" ::: "memory");
        __builtin_amdgcn_sched_barrier(0);             // rule #18

        bf16x8 blA[4] = { bl0, bl1, bl2, bl3 };

        // ---- gates GEMM, biases folded into accumulator init
        f32x4 acc[8];
        #pragma unroll
        for (int mt = 0; mt < 4; ++mt) {
            acc[mt]     = *(const f32x4*)(bfb + mt * 16 + quad * 4);
            acc[mt + 4] = *(const f32x4*)(bgb + mt * 16 + quad * 4);
        }
        #pragma unroll
        for (int ks = 0; ks < 4; ++ks) {
            #pragma unroll
            for (int mt = 0; mt < 8; ++mt) {
                BF8 af; af.u4 = *(const uint4v*)(PW + (((mt << 2) + ks) * 64 + l) * 8);
                acc[mt] = __builtin_amdgcn_mfma_f32_16x16x32_bf16(af.v, blA[ks], acc[mt], 0, 0, 0);
            }
        }

        // ---- z = tanh(f)*sigmoid(g) -> ZB (rcp for divisions; bf16 -> ZB row nloc)
        #pragma unroll
        for (int mt = 0; mt < 4; ++mt) {
            f32x4 z;
            #pragma unroll
            for (int r = 0; r < 4; ++r) {
                float f = acc[mt][r];
                float g = acc[mt + 4][r];
                float e2 = __expf(2.0f * f);
                float th = 1.0f - 2.0f * __builtin_amdgcn_rcpf(e2 + 1.0f);
                float sg = __builtin_amdgcn_rcpf(1.0f + __expf(-g));
                z[r] = th * sg;
            }
            *(u64_t*)(ZB + nloc * 72 + mt * 16 + quad * 4) = pk4(z);
        }
        // ZB is wave-private (each wave reads only rows it wrote): wave-local wait
        asm volatile("s_waitcnt lgkmcnt(0)" ::: "memory");
        __builtin_amdgcn_sched_barrier(0);

        // ---- res/skip GEMM, biases in acc init
        f32x4 acc2[8];
        #pragma unroll
        for (int mt = 0; mt < 4; ++mt) {
            acc2[mt]     = *(const f32x4*)(brb + mt * 16 + quad * 4);
            acc2[mt + 4] = *(const f32x4*)(bsb + mt * 16 + quad * 4);
        }
        const ushort_t* PRS = PW + 16384;
        #pragma unroll
        for (int ks = 0; ks < 2; ++ks) {
            BF8 t; t.u4 = *(const uint4v*)(ZB + nloc * 72 + ks * 32 + quad * 8);
            #pragma unroll
            for (int mt = 0; mt < 8; ++mt) {
                BF8 af; af.u4 = *(const uint4v*)(PRS + (((mt << 1) + ks) * 64 + l) * 8);
                acc2[mt] = __builtin_amdgcn_mfma_f32_16x16x32_bf16(af.v, t.v, acc2[mt], 0, 0, 0);
            }
        }

        // ---- epilogue: hreg = res + right (fp32 regs); bf16 -> HT[nxt] (+ halo)
        #pragma unroll
        for (int mt = 0; mt < 4; ++mt) {
            #pragma unroll
            for (int r = 0; r < 4; ++r) {
                hreg[mt][r] = acc2[mt][r] + hreg[mt][r];
                skip_acc[mt][r] += acc2[mt + 4][r];
            }
        }
        if (i < NLAYERS - 1) {
            #pragma unroll
            for (int mt = 0; mt < 4; ++mt) {
                u64_t pk = pk4(hreg[mt]);
                *HTW(nxt, nloc, mt, quad) = pk;
                if (nloc >= 128 - hn) {
                    ushort_t* dst = haloOut + (tau0 + nloc) * 64 + mt * 16 + quad * 4;
                    asm volatile("global_store_dwordx2 %0, %1, off sc1"
                                 :: "v"(dst), "v"(pk) : "memory");
                }
            }
        }

        // ---- publish layer completion (halo at LLC after per-wave vmcnt + barrier)
        asm volatile("s_waitcnt vmcnt(0)" ::: "memory");
        __syncthreads();   // C: all waves' halo stores drained; HT[nxt] writes visible
        if (i < NLAYERS - 1 && tid == 0)
            __hip_atomic_store(&flags[blk << 5], (unsigned)(i + 2), __ATOMIC_RELAXED,
                               __HIP_MEMORY_SCOPE_AGENT);
    }

    // ---- output head (block-local; skip in regs; ZB reused — all rows wave-private)
    asm volatile("s_waitcnt lgkmcnt(0)" ::: "memory");   // last layer's ZB reads done
    #pragma unroll
    for (int mt = 0; mt < 4; ++mt) {
        f32x4 a = *(const f32x4*)(alpha + mt * 16 + quad * 4);
        f32x4 y;
        #pragma unroll
        for (int r = 0; r < 4; ++r) {
            float x = skip_acc[mt][r];
            y[r] = x > 0.0f ? x : a[r] * x;
        }
        *(u64_t*)(ZB + nloc * 72 + mt * 16 + quad * 4) = pk4(y);
    }
    asm volatile("s_waitcnt lgkmcnt(0)" ::: "memory");
    __builtin_amdgcn_sched_barrier(0);

    const ushort_t* PW0 = pbf + PBF_LAYERS;
    const ushort_t* PW1 = PW0 + 4096;

    // W0 GEMM (64x64), bias in acc init
    f32x4 acc0[4];
    #pragma unroll
    for (int mt = 0; mt < 4; ++mt) acc0[mt] = *(const f32x4*)(b_out0 + mt * 16 + quad * 4);
    #pragma unroll
    for (int ks = 0; ks < 2; ++ks) {
        BF8 t; t.u4 = *(const uint4v*)(ZB + nloc * 72 + ks * 32 + quad * 8);
        #pragma unroll
        for (int mt = 0; mt < 4; ++mt) {
            BF8 af; af.u4 = *(const uint4v*)(PW0 + (((mt << 1) + ks) * 64 + l) * 8);
            acc0[mt] = __builtin_amdgcn_mfma_f32_16x16x32_bf16(af.v, t.v, acc0[mt], 0, 0, 0);
        }
    }
    asm volatile("s_waitcnt lgkmcnt(0)" ::: "memory");   // W0 reads done before overwrite

    // lrelu_alpha1 -> X1 back into ZB (wave-private rows)
    #pragma unroll
    for (int mt = 0; mt < 4; ++mt) {
        f32x4 a = *(const f32x4*)(alpha + 64 + mt * 16 + quad * 4);
        f32x4 y;
        #pragma unroll
        for (int r = 0; r < 4; ++r) {
            float x = acc0[mt][r];
            y[r] = x > 0.0f ? x : a[r] * x;
        }
        *(u64_t*)(ZB + nloc * 72 + mt * 16 + quad * 4) = pk4(y);
    }
    asm volatile("s_waitcnt lgkmcnt(0)" ::: "memory");
    __builtin_amdgcn_sched_barrier(0);

    // W1 GEMM (256x64), bias in acc init
    f32x4 acc1[16];
    #pragma unroll
    for (int mt = 0; mt < 16; ++mt) acc1[mt] = *(const f32x4*)(b_out1 + mt * 16 + quad * 4);
    #pragma unroll
    for (int ks = 0; ks < 2; ++ks) {
        BF8 t; t.u4 = *(const uint4v*)(ZB + nloc * 72 + ks * 32 + quad * 8);
        #pragma unroll
        for (int mt = 0; mt < 16; ++mt) {
            BF8 af; af.u4 = *(const uint4v*)(PW1 + (((mt << 1) + ks) * 64 + l) * 8);
            acc1[mt] = __builtin_amdgcn_mfma_f32_16x16x32_bf16(af.v, t.v, acc1[mt], 0, 0, 0);
        }
    }

    int u = tau0 + nloc - OUT_START;
    if (u >= 0) {
        #pragma unroll
        for (int mt = 0; mt < 16; ++mt)
            #pragma unroll
            for (int r = 0; r < 4; ++r)
                out[(mt * 16 + quad * 4 + r) * OUT_W + u] = acc1[mt][r];
    }
#undef HTP
#undef HTW
}

// ---------------------------------------------------------------- launch
extern "C" void kernel_launch(void* const* d_in, const int* in_sizes, int n_in,
                              void* d_out, int out_size, void* d_ws, size_t ws_size,
                              hipStream_t stream)
{
    const float* input  = (const float*)d_in[0];
    const float* w0     = (const float*)d_in[1];
    const float* b0     = (const float*)d_in[2];
    const float* wf     = (const float*)d_in[3];
    const float* bf     = (const float*)d_in[4];
    const float* wg     = (const float*)d_in[5];
    const float* bg     = (const float*)d_in[6];
    const float* wr     = (const float*)d_in[7];
    const float* br     = (const float*)d_in[8];
    const float* wsk    = (const float*)d_in[9];
    const float* bs     = (const float*)d_in[10];
    const float* alpha  = (const float*)d_in[11];
    const float* w_out0 = (const float*)d_in[12];
    const float* b_out0 = (const float*)d_in[13];
    const float* w_out1 = (const float*)d_in[14];
    const float* b_out1 = (const float*)d_in[15];
    float* outp = (float*)d_out;

    float* wsbase = (float*)d_ws;
    ushort_t* pbf = (ushort_t*)wsbase;
    ushort_t* HALO0 = (ushort_t*)(wsbase + HALO0_OFF);
    ushort_t* HALO1 = (ushort_t*)(wsbase + HALO1_OFF);
    unsigned* flags = (unsigned*)(wsbase + FLAG_OFF);

    pack_mfma<<<PBF_TOTAL / 256, 256, 0, stream>>>(wf, wg, wr, wsk, w_out0, w_out1, pbf, flags);

    wavenet_fused<<<dim3(NBLOCKS), dim3(512), 0, stream>>>(
        input, w0, b0, pbf, bf, bg, br, bs, alpha, b_out0, b_out1,
        HALO0, HALO1, outp, flags);
}

// Round 12
// 458.417 us; speedup vs baseline: 1.3193x; 1.0024x over previous
//
#include <hip/hip_runtime.h>

typedef unsigned short ushort_t;
typedef unsigned long long u64_t;
typedef __attribute__((ext_vector_type(8))) __bf16 bf16x8;
typedef __attribute__((ext_vector_type(4))) __bf16 bf16x4;
typedef __attribute__((ext_vector_type(4))) float f32x4;
typedef __attribute__((ext_vector_type(4))) unsigned int uint4v;

#define T_TOTAL 65536
#define NLAYERS 20
#define OUT_START 2047
#define OUT_W 63489
#define NBLOCKS 512

// workspace layout (floats)
#define PBF_PER_LAYER 24576
#define PBF_LAYERS (NLAYERS * PBF_PER_LAYER)        // 491520 ushorts
#define PBF_TOTAL (PBF_LAYERS + 4096 + 16384)       // 512000 ushorts
#define HALO_OFF 524288                              // float offset of halo ring
#define HALO_USHORTS (T_TOTAL * 64)                  // one bf16 halo buffer = 8 MB
#define HALO_FLOATS (HALO_USHORTS / 2)
#define FLAG_OFF (HALO_OFF + 4 * HALO_FLOATS)        // 512 flags, 128B apart

__device__ __forceinline__ ushort_t f2bf(float x) {
    union { float f; unsigned u; } c; c.f = x;
    unsigned u = c.u + 0x7FFFu + ((c.u >> 16) & 1u);   // RNE
    return (ushort_t)(u >> 16);
}

union BF8 { uint4v u4; bf16x8 v; };

// HW bf16 pack (compiler emits v_cvt_pk_bf16_f32, RNE)
__device__ __forceinline__ u64_t pk4(f32x4 v) {
    union { bf16x4 b; u64_t u; } r;
    r.b[0] = (__bf16)v[0]; r.b[1] = (__bf16)v[1];
    r.b[2] = (__bf16)v[2]; r.b[3] = (__bf16)v[3];
    return r.u;
}

// ---------------------------------------------------------------- pack ALL MFMA weights (bf16, A-fragment order)
__global__ __launch_bounds__(256) void pack_mfma(
    const float* __restrict__ wf, const float* __restrict__ wg,
    const float* __restrict__ wr, const float* __restrict__ wsk,
    const float* __restrict__ w0h, const float* __restrict__ w1h,
    ushort_t* __restrict__ out, unsigned* __restrict__ flags)
{
    int idx = blockIdx.x * 256 + threadIdx.x;
    if (idx < NBLOCKS) flags[idx << 5] = 0u;   // reset progress flags every launch (replay-safe)
    if (idx >= PBF_TOTAL) return;
    float v;
    if (idx < PBF_LAYERS) {
        int i = idx / PBF_PER_LAYER;
        int r = idx - i * PBF_PER_LAYER;
        if (r < 16384) {                  // gates A (128x128 = [f;g] x [left||right])
            int j = r & 7, l = (r >> 3) & 63, ks = (r >> 9) & 3, mt = r >> 11;
            int m = mt * 16 + (l & 15);
            int k = ks * 32 + ((l >> 4) << 3) + j;
            int o = m & 63, c = k & 63, half = k >> 6;
            const float* src = (m < 64) ? wf : wg;
            v = src[(((i * 64 + o) * 64 + c) << 1) + half];
        } else {                          // rs A (128x64 = [r;s] x c)
            int rr = r - 16384;
            int j = rr & 7, l = (rr >> 3) & 63, ks = (rr >> 9) & 1, mt = rr >> 10;
            int m = mt * 16 + (l & 15);
            int k = ks * 32 + ((l >> 4) << 3) + j;
            v = (m < 64) ? wr[(i * 64 + m) * 64 + k] : wsk[(i * 64 + (m - 64)) * 64 + k];
        }
    } else if (idx < PBF_LAYERS + 4096) { // W0 head (64x64)
        int rr = idx - PBF_LAYERS;
        int j = rr & 7, l = (rr >> 3) & 63, ks = (rr >> 9) & 1, mt = rr >> 10;
        int m = mt * 16 + (l & 15);
        int k = ks * 32 + ((l >> 4) << 3) + j;
        v = w0h[m * 64 + k];
    } else {                              // W1 head (256x64)
        int rr = idx - PBF_LAYERS - 4096;
        int j = rr & 7, l = (rr >> 3) & 63, ks = (rr >> 9) & 1, mt = rr >> 10;
        int m = mt * 16 + (l & 15);
        int k = ks * 32 + ((l >> 4) << 3) + j;
        v = w1h[m * 64 + k];
    }
    out[idx] = f2bf(v);
}

// ---------------------------------------------------------------- fused persistent kernel
// R11/R12 (on R10, fused 379us, ALL pipes <15% => stall-bound): R10's 2-buffer
// halo forces a bidirectional SAME-LAYER wait (producers AND anti-dep readers
// at flag >= i+1) -> the entire grid advances in lockstep; every block stalls
// on the same per-layer sync chain and co-resident blocks stall at the same
// phase, so CUs go idle. Fix: 4-DEEP HALO RING (layer j reads HALO[j%4]; end
// of layer i writes HALO[(i+1)%4]) -> the buffer overwritten at layer i was
// last read at layer i-3, so the forward wait weakens to flag[b+k] >= i-1
// (3 layers of slack; none for i<3; none at i=19 which writes nothing).
// Blocks skew into a forward-leaning pipeline; the only hard edges are the
// 20 producer hops. No deadlock: a wait cycle needs j < i-2 and j > i.
// Everything else identical to R10 (bf16 LDS H, fp32 residual in regs,
// rcp activations, fence-free sc1/LLC exchange, relaxed flags).
// (R11 bench was an infra failure — container never booted; kernel re-audited
// clean: ring indexing, anti-dep targets, workspace bounds, deadlock-freedom.)
__global__ __launch_bounds__(512, 4) void wavenet_fused(
    const float* __restrict__ in, const float* __restrict__ w0v, const float* __restrict__ b0v,
    const ushort_t* __restrict__ pbf,
    const float* __restrict__ bf_all, const float* __restrict__ bg_all,
    const float* __restrict__ br_all, const float* __restrict__ bs_all,
    const float* __restrict__ alpha, const float* __restrict__ b_out0,
    const float* __restrict__ b_out1,
    ushort_t* __restrict__ HB, float* __restrict__ out, unsigned* flags)
{
    __shared__ alignas(16) ushort_t HT[2 * 128 * 64];   // 32 KB bf16 H, double-buffered
    __shared__ alignas(16) ushort_t ZB[128 * 72];       // 18 KB z staging (head reuses)

    const int tid = threadIdx.x;
    const int l = tid & 63, w = tid >> 6;          // 8 waves
    const int l15 = l & 15, quad = l >> 4;
    const int bid = (int)blockIdx.x;
    const int blk = (bid & 7) * 64 + (bid >> 3);   // XCD-chunked swizzle
    const int tau0 = blk * 128;
    const int tauW = tau0 + w * 16 + l15;          // this wave's 16-row tile
    const int nloc = w * 16 + l15;                 // local row (0..127)

// 16B bf16 granule g (0..7) of row r in buffer c, XOR-swizzled by row
#define HTP(c, r, g) ((const uint4v*)((char*)HT + ((c) << 14) + ((r) << 7) + ((((g) ^ ((r) & 7))) << 4)))
// u64 write slot for ch chunk mt*16+quad*4 of row r in buffer c
#define HTW(c, r, mt, q) ((u64_t*)((char*)HT + ((c) << 14) + ((r) << 7) + ((((2 * (mt) + ((q) >> 1)) ^ ((r) & 7))) << 4) + (((q) & 1) << 3)))

    // ---- init: thread owns row nloc, ch chunks mt*16+quad*4; fp32 in hreg,
    //      bf16 into HT[0]; row 127 published to halo ring buffer 0 (d_0 = 1)
    f32x4 hreg[4];
    {
        float x = in[tau0 + nloc];
        #pragma unroll
        for (int mt = 0; mt < 4; ++mt) {
            int c0 = mt * 16 + quad * 4;
            f32x4 wv = *(const f32x4*)(w0v + c0);
            f32x4 bv = *(const f32x4*)(b0v + c0);
            #pragma unroll
            for (int r = 0; r < 4; ++r) hreg[mt][r] = fmaf(wv[r], x, bv[r]);
            u64_t pk = pk4(hreg[mt]);
            *HTW(0, nloc, mt, quad) = pk;
            if (nloc == 127) {
                ushort_t* dst = HB + (tau0 + 127) * 64 + c0;
                asm volatile("global_store_dwordx2 %0, %1, off sc1" :: "v"(dst), "v"(pk) : "memory");
            }
        }
    }
    asm volatile("s_waitcnt vmcnt(0)" ::: "memory");
    __syncthreads();
    if (tid == 0)
        __hip_atomic_store(&flags[blk << 5], 1u, __ATOMIC_RELAXED, __HIP_MEMORY_SCOPE_AGENT);

    f32x4 skip_acc[4];
    #pragma unroll
    for (int mt = 0; mt < 4; ++mt) skip_acc[mt] = (f32x4){0.0f, 0.0f, 0.0f, 0.0f};

    #pragma unroll 1
    for (int i = 0; i < NLAYERS; ++i) {
        const int cur = i & 1, nxt = cur ^ 1;
        const int d = 1 << (i >= 10 ? i - 10 : i);
        const int ip1 = i + 1;
        const int dnext = (ip1 < NLAYERS) ? (1 << (ip1 >= 10 ? ip1 - 10 : ip1)) : 0;
        const int hn = dnext > 128 ? 128 : dnext;      // rows to publish for next layer
        const int nleft = (d + 127) >> 7;              // producers needed (<=4)
        // anti-dep: buffer (i+1)%4 was last READ at layer i-3 by blocks b+k,
        // k <= ceil(d_{i-3}/128); they are done once flag >= (i-3)+2 = i-1.
        const int di3 = (i >= 3) ? (1 << ((i - 3) >= 10 ? i - 13 : i - 3)) : 0;
        const int nr3 = (di3 + 127) >> 7;
        const ushort_t* haloIn = HB + (unsigned)(i & 3) * HALO_USHORTS;
        ushort_t* haloOut = HB + (unsigned)((i + 1) & 3) * HALO_USHORTS;

        // ---- wait for neighbor progress (relaxed polls of LLC; no fences)
        if (w == 0) {
            int nb = -1; unsigned tgt = 0;
            if (l < 4) {
                int k = l + 1;
                if (k <= nleft) { nb = blk - k; tgt = (unsigned)(i + 1); }
            } else if (l < 8 && i >= 3 && i < NLAYERS - 1) {
                int k = l - 3;
                if (k <= nr3) { nb = blk + k; tgt = (unsigned)(i - 1); }
            }
            if (nb >= 0 && nb < NBLOCKS) {
                while (__hip_atomic_load(&flags[nb << 5], __ATOMIC_RELAXED,
                                         __HIP_MEMORY_SCOPE_AGENT) < tgt)
                    __builtin_amdgcn_s_sleep(1);
            }
        }
        __syncthreads();   // A: poll done; also orders prev-layer HT[cur] writes before reads

        const ushort_t* PW = pbf + i * PBF_PER_LAYER;
        const float* bfb = bf_all + i * 64;
        const float* bgb = bg_all + i * 64;
        const float* brb = br_all + i * 64;
        const float* bsb = bs_all + i * 64;

        // ---- gate B operands: left from halo (bf16 global) or HT[cur]; own from HT[cur]
        int grow = tauW - d; if (grow < 0) grow = 0;
        bf16x8 bl0, bl1, bl2, bl3;
        if (grow < tau0) {
            const ushort_t* hp = haloIn + grow * 64 + quad * 8;
            asm volatile(
                "global_load_dwordx4 %0, %2, off sc1\n\t"
                "global_load_dwordx4 %1, %2, off offset:64 sc1"
                : "=&v"(bl0), "=&v"(bl1) : "v"(hp) : "memory");
        } else {
            int rl = grow - tau0;
            BF8 a0, a1;
            a0.u4 = *HTP(cur, rl, quad);
            a1.u4 = *HTP(cur, rl, 4 + quad);
            bl0 = a0.v; bl1 = a1.v;
        }
        {
            BF8 b0, b1;
            b0.u4 = *HTP(cur, nloc, quad);
            b1.u4 = *HTP(cur, nloc, 4 + quad);
            bl2 = b0.v; bl3 = b1.v;
        }
        asm volatile("s_waitcnt vmcnt(0) lgkmcnt(0)" ::: "memory");
        __builtin_amdgcn_sched_barrier(0);             // rule #18

        bf16x8 blA[4] = { bl0, bl1, bl2, bl3 };

        // ---- gates GEMM, biases folded into accumulator init
        f32x4 acc[8];
        #pragma unroll
        for (int mt = 0; mt < 4; ++mt) {
            acc[mt]     = *(const f32x4*)(bfb + mt * 16 + quad * 4);
            acc[mt + 4] = *(const f32x4*)(bgb + mt * 16 + quad * 4);
        }
        #pragma unroll
        for (int ks = 0; ks < 4; ++ks) {
            #pragma unroll
            for (int mt = 0; mt < 8; ++mt) {
                BF8 af; af.u4 = *(const uint4v*)(PW + (((mt << 2) + ks) * 64 + l) * 8);
                acc[mt] = __builtin_amdgcn_mfma_f32_16x16x32_bf16(af.v, blA[ks], acc[mt], 0, 0, 0);
            }
        }

        // ---- z = tanh(f)*sigmoid(g) -> ZB (rcp for divisions; bf16 -> ZB row nloc)
        #pragma unroll
        for (int mt = 0; mt < 4; ++mt) {
            f32x4 z;
            #pragma unroll
            for (int r = 0; r < 4; ++r) {
                float f = acc[mt][r];
                float g = acc[mt + 4][r];
                float e2 = __expf(2.0f * f);
                float th = 1.0f - 2.0f * __builtin_amdgcn_rcpf(e2 + 1.0f);
                float sg = __builtin_amdgcn_rcpf(1.0f + __expf(-g));
                z[r] = th * sg;
            }
            *(u64_t*)(ZB + nloc * 72 + mt * 16 + quad * 4) = pk4(z);
        }
        // ZB is wave-private (each wave reads only rows it wrote): wave-local wait
        asm volatile("s_waitcnt lgkmcnt(0)" ::: "memory");
        __builtin_amdgcn_sched_barrier(0);

        // ---- res/skip GEMM, biases in acc init
        f32x4 acc2[8];
        #pragma unroll
        for (int mt = 0; mt < 4; ++mt) {
            acc2[mt]     = *(const f32x4*)(brb + mt * 16 + quad * 4);
            acc2[mt + 4] = *(const f32x4*)(bsb + mt * 16 + quad * 4);
        }
        const ushort_t* PRS = PW + 16384;
        #pragma unroll
        for (int ks = 0; ks < 2; ++ks) {
            BF8 t; t.u4 = *(const uint4v*)(ZB + nloc * 72 + ks * 32 + quad * 8);
            #pragma unroll
            for (int mt = 0; mt < 8; ++mt) {
                BF8 af; af.u4 = *(const uint4v*)(PRS + (((mt << 1) + ks) * 64 + l) * 8);
                acc2[mt] = __builtin_amdgcn_mfma_f32_16x16x32_bf16(af.v, t.v, acc2[mt], 0, 0, 0);
            }
        }

        // ---- epilogue: hreg = res + right (fp32 regs); bf16 -> HT[nxt] (+ halo)
        #pragma unroll
        for (int mt = 0; mt < 4; ++mt) {
            #pragma unroll
            for (int r = 0; r < 4; ++r) {
                hreg[mt][r] = acc2[mt][r] + hreg[mt][r];
                skip_acc[mt][r] += acc2[mt + 4][r];
            }
        }
        if (i < NLAYERS - 1) {
            #pragma unroll
            for (int mt = 0; mt < 4; ++mt) {
                u64_t pk = pk4(hreg[mt]);
                *HTW(nxt, nloc, mt, quad) = pk;
                if (nloc >= 128 - hn) {
                    ushort_t* dst = haloOut + (tau0 + nloc) * 64 + mt * 16 + quad * 4;
                    asm volatile("global_store_dwordx2 %0, %1, off sc1"
                                 :: "v"(dst), "v"(pk) : "memory");
                }
            }
        }

        // ---- publish layer completion (halo at LLC after vmcnt + barrier)
        asm volatile("s_waitcnt vmcnt(0)" ::: "memory");
        __syncthreads();   // C: all waves' halo stores drained; HT[nxt] writes visible
        if (i < NLAYERS - 1 && tid == 0)
            __hip_atomic_store(&flags[blk << 5], (unsigned)(i + 2), __ATOMIC_RELAXED,
                               __HIP_MEMORY_SCOPE_AGENT);
    }

    // ---- output head (block-local; skip in regs; ZB reused — all rows wave-private)
    asm volatile("s_waitcnt lgkmcnt(0)" ::: "memory");   // last layer's ZB reads done
    #pragma unroll
    for (int mt = 0; mt < 4; ++mt) {
        f32x4 a = *(const f32x4*)(alpha + mt * 16 + quad * 4);
        f32x4 y;
        #pragma unroll
        for (int r = 0; r < 4; ++r) {
            float x = skip_acc[mt][r];
            y[r] = x > 0.0f ? x : a[r] * x;
        }
        *(u64_t*)(ZB + nloc * 72 + mt * 16 + quad * 4) = pk4(y);
    }
    asm volatile("s_waitcnt lgkmcnt(0)" ::: "memory");
    __builtin_amdgcn_sched_barrier(0);

    const ushort_t* PW0 = pbf + PBF_LAYERS;
    const ushort_t* PW1 = PW0 + 4096;

    // W0 GEMM (64x64), bias in acc init
    f32x4 acc0[4];
    #pragma unroll
    for (int mt = 0; mt < 4; ++mt) acc0[mt] = *(const f32x4*)(b_out0 + mt * 16 + quad * 4);
    #pragma unroll
    for (int ks = 0; ks < 2; ++ks) {
        BF8 t; t.u4 = *(const uint4v*)(ZB + nloc * 72 + ks * 32 + quad * 8);
        #pragma unroll
        for (int mt = 0; mt < 4; ++mt) {
            BF8 af; af.u4 = *(const uint4v*)(PW0 + (((mt << 1) + ks) * 64 + l) * 8);
            acc0[mt] = __builtin_amdgcn_mfma_f32_16x16x32_bf16(af.v, t.v, acc0[mt], 0, 0, 0);
        }
    }
    asm volatile("s_waitcnt lgkmcnt(0)" ::: "memory");   // W0 reads done before overwrite

    // lrelu_alpha1 -> X1 back into ZB (wave-private rows)
    #pragma unroll
    for (int mt = 0; mt < 4; ++mt) {
        f32x4 a = *(const f32x4*)(alpha + 64 + mt * 16 + quad * 4);
        f32x4 y;
        #pragma unroll
        for (int r = 0; r < 4; ++r) {
            float x = acc0[mt][r];
            y[r] = x > 0.0f ? x : a[r] * x;
        }
        *(u64_t*)(ZB + nloc * 72 + mt * 16 + quad * 4) = pk4(y);
    }
    asm volatile("s_waitcnt lgkmcnt(0)" ::: "memory");
    __builtin_amdgcn_sched_barrier(0);

    // W1 GEMM (256x64), bias in acc init
    f32x4 acc1[16];
    #pragma unroll
    for (int mt = 0; mt < 16; ++mt) acc1[mt] = *(const f32x4*)(b_out1 + mt * 16 + quad * 4);
    #pragma unroll
    for (int ks = 0; ks < 2; ++ks) {
        BF8 t; t.u4 = *(const uint4v*)(ZB + nloc * 72 + ks * 32 + quad * 8);
        #pragma unroll
        for (int mt = 0; mt < 16; ++mt) {
            BF8 af; af.u4 = *(const uint4v*)(PW1 + (((mt << 1) + ks) * 64 + l) * 8);
            acc1[mt] = __builtin_amdgcn_mfma_f32_16x16x32_bf16(af.v, t.v, acc1[mt], 0, 0, 0);
        }
    }

    int u = tau0 + nloc - OUT_START;
    if (u >= 0) {
        #pragma unroll
        for (int mt = 0; mt < 16; ++mt)
            #pragma unroll
            for (int r = 0; r < 4; ++r)
                out[(mt * 16 + quad * 4 + r) * OUT_W + u] = acc1[mt][r];
    }
#undef HTP
#undef HTW
}

// ---------------------------------------------------------------- launch
extern "C" void kernel_launch(void* const* d_in, const int* in_sizes, int n_in,
                              void* d_out, int out_size, void* d_ws, size_t ws_size,
                              hipStream_t stream)
{
    const float* input  = (const float*)d_in[0];
    const float* w0     = (const float*)d_in[1];
    const float* b0     = (const float*)d_in[2];
    const float* wf     = (const float*)d_in[3];
    const float* bf     = (const float*)d_in[4];
    const float* wg     = (const float*)d_in[5];
    const float* bg     = (const float*)d_in[6];
    const float* wr     = (const float*)d_in[7];
    const float* br     = (const float*)d_in[8];
    const float* wsk    = (const float*)d_in[9];
    const float* bs     = (const float*)d_in[10];
    const float* alpha  = (const float*)d_in[11];
    const float* w_out0 = (const float*)d_in[12];
    const float* b_out0 = (const float*)d_in[13];
    const float* w_out1 = (const float*)d_in[14];
    const float* b_out1 = (const float*)d_in[15];
    float* outp = (float*)d_out;

    float* wsbase = (float*)d_ws;
    ushort_t* pbf = (ushort_t*)wsbase;
    ushort_t* HB = (ushort_t*)(wsbase + HALO_OFF);
    unsigned* flags = (unsigned*)(wsbase + FLAG_OFF);

    pack_mfma<<<PBF_TOTAL / 256, 256, 0, stream>>>(wf, wg, wr, wsk, w_out0, w_out1, pbf, flags);

    wavenet_fused<<<dim3(NBLOCKS), dim3(512), 0, stream>>>(
        input, w0, b0, pbf, bf, bg, br, bs, alpha, b_out0, b_out1,
        HB, outp, flags);
}

// Round 13
// 381.563 us; speedup vs baseline: 1.5851x; 1.2014x over previous
//
#include <hip/hip_runtime.h>

typedef unsigned short ushort_t;
typedef unsigned long long u64_t;
typedef __attribute__((ext_vector_type(8))) __bf16 bf16x8;
typedef __attribute__((ext_vector_type(4))) __bf16 bf16x4;
typedef __attribute__((ext_vector_type(4))) float f32x4;
typedef __attribute__((ext_vector_type(4))) unsigned int uint4v;

#define T_TOTAL 65536
#define NLAYERS 20
#define OUT_START 2047
#define OUT_W 63489
#define NBLOCKS 512

// workspace layout (floats)
#define PBF_PER_LAYER 24576
#define PBF_LAYERS (NLAYERS * PBF_PER_LAYER)        // 491520 ushorts
#define PBF_TOTAL (PBF_LAYERS + 4096 + 16384)       // 512000 ushorts
#define HALO_OFF 524288                              // float offset of halo ring
#define HALO_USHORTS (T_TOTAL * 64)                  // one bf16 halo buffer = 8 MB
#define HALO_FLOATS (HALO_USHORTS / 2)
#define FLAG_OFF (HALO_OFF + 4 * HALO_FLOATS)        // 512 flags, 128B apart

__device__ __forceinline__ ushort_t f2bf(float x) {
    union { float f; unsigned u; } c; c.f = x;
    unsigned u = c.u + 0x7FFFu + ((c.u >> 16) & 1u);   // RNE
    return (ushort_t)(u >> 16);
}

union BF8 { uint4v u4; bf16x8 v; };

// HW bf16 pack (compiler emits v_cvt_pk_bf16_f32, RNE)
__device__ __forceinline__ u64_t pk4(f32x4 v) {
    union { bf16x4 b; u64_t u; } r;
    r.b[0] = (__bf16)v[0]; r.b[1] = (__bf16)v[1];
    r.b[2] = (__bf16)v[2]; r.b[3] = (__bf16)v[3];
    return r.u;
}

// ---------------------------------------------------------------- pack ALL MFMA weights (bf16, A-fragment order)
__global__ __launch_bounds__(256) void pack_mfma(
    const float* __restrict__ wf, const float* __restrict__ wg,
    const float* __restrict__ wr, const float* __restrict__ wsk,
    const float* __restrict__ w0h, const float* __restrict__ w1h,
    ushort_t* __restrict__ out, unsigned* __restrict__ flags)
{
    int idx = blockIdx.x * 256 + threadIdx.x;
    if (idx < NBLOCKS) flags[idx << 5] = 0u;   // reset progress flags every launch (replay-safe)
    if (idx >= PBF_TOTAL) return;
    float v;
    if (idx < PBF_LAYERS) {
        int i = idx / PBF_PER_LAYER;
        int r = idx - i * PBF_PER_LAYER;
        if (r < 16384) {                  // gates A (128x128 = [f;g] x [left||right])
            int j = r & 7, l = (r >> 3) & 63, ks = (r >> 9) & 3, mt = r >> 11;
            int m = mt * 16 + (l & 15);
            int k = ks * 32 + ((l >> 4) << 3) + j;
            int o = m & 63, c = k & 63, half = k >> 6;
            const float* src = (m < 64) ? wf : wg;
            v = src[(((i * 64 + o) * 64 + c) << 1) + half];
        } else {                          // rs A (128x64 = [r;s] x c)
            int rr = r - 16384;
            int j = rr & 7, l = (rr >> 3) & 63, ks = (rr >> 9) & 1, mt = rr >> 10;
            int m = mt * 16 + (l & 15);
            int k = ks * 32 + ((l >> 4) << 3) + j;
            v = (m < 64) ? wr[(i * 64 + m) * 64 + k] : wsk[(i * 64 + (m - 64)) * 64 + k];
        }
    } else if (idx < PBF_LAYERS + 4096) { // W0 head (64x64)
        int rr = idx - PBF_LAYERS;
        int j = rr & 7, l = (rr >> 3) & 63, ks = (rr >> 9) & 1, mt = rr >> 10;
        int m = mt * 16 + (l & 15);
        int k = ks * 32 + ((l >> 4) << 3) + j;
        v = w0h[m * 64 + k];
    } else {                              // W1 head (256x64)
        int rr = idx - PBF_LAYERS - 4096;
        int j = rr & 7, l = (rr >> 3) & 63, ks = (rr >> 9) & 1, mt = rr >> 10;
        int m = mt * 16 + (l & 15);
        int k = ks * 32 + ((l >> 4) << 3) + j;
        v = w1h[m * 64 + k];
    }
    out[idx] = f2bf(v);
}

// ---------------------------------------------------------------- fused persistent kernel
// R13 (on R12, fused ~379us; R10==R12 null killed the sync-slack theory):
// remaining unpriced cost = the A-fragment WEIGHT STREAM. Every wave re-reads
// the full 48KB layer panel from global per layer; 16 waves/CU x 48KB =
// 768KB/CU/layer, streaming from L2 (panel > 32KB L1) ~= 5.7us/layer per XCD
// plus exposed miss latency. Fix: 256 threads / 4 waves, each wave owns TWO
// 16-col tiles (nt=0,1) and each A-fragment load feeds BOTH tiles' MFMAs ->
// per-CU weight traffic halves (384KB/layer), MFMA work unchanged.
// Asymmetric read: big win => weight stream confirmed (next: LDS-stage
// weights); null (>=365us) => H1 dead, attack per-hop sync latency next.
// Everything else identical to R12 (bf16 LDS H, fp32 residual in regs, rcp
// activations, 4-deep halo ring, fence-free sc1/LLC exchange, relaxed flags).
__global__ __launch_bounds__(256, 2) void wavenet_fused(
    const float* __restrict__ in, const float* __restrict__ w0v, const float* __restrict__ b0v,
    const ushort_t* __restrict__ pbf,
    const float* __restrict__ bf_all, const float* __restrict__ bg_all,
    const float* __restrict__ br_all, const float* __restrict__ bs_all,
    const float* __restrict__ alpha, const float* __restrict__ b_out0,
    const float* __restrict__ b_out1,
    ushort_t* __restrict__ HB, float* __restrict__ out, unsigned* flags)
{
    __shared__ alignas(16) ushort_t HT[2 * 128 * 64];   // 32 KB bf16 H, double-buffered
    __shared__ alignas(16) ushort_t ZB[128 * 72];       // 18 KB z staging (head reuses)

    const int tid = threadIdx.x;
    const int l = tid & 63, w = tid >> 6;          // 4 waves
    const int l15 = l & 15, quad = l >> 4;
    const int bid = (int)blockIdx.x;
    const int blk = (bid & 7) * 64 + (bid >> 3);   // XCD-chunked swizzle
    const int tau0 = blk * 128;
    const int nloc0 = w * 32 + l15;                // wave's tile 0 row (0..127)
    const int nloc1 = nloc0 + 16;                  // wave's tile 1 row
    const int tauN0 = tau0 + nloc0;
    const int tauN1 = tau0 + nloc1;

// 16B bf16 granule g (0..7) of row r in buffer c, XOR-swizzled by row
#define HTP(c, r, g) ((const uint4v*)((char*)HT + ((c) << 14) + ((r) << 7) + ((((g) ^ ((r) & 7))) << 4)))
// u64 write slot for ch chunk mt*16+quad*4 of row r in buffer c
#define HTW(c, r, mt, q) ((u64_t*)((char*)HT + ((c) << 14) + ((r) << 7) + ((((2 * (mt) + ((q) >> 1)) ^ ((r) & 7))) << 4) + (((q) & 1) << 3)))

    // ---- init: thread owns rows nloc0/nloc1, ch chunks mt*16+quad*4; fp32 in
    //      hreg, bf16 into HT[0]; row 127 published to halo ring buffer 0 (d_0=1)
    f32x4 hreg[4][2];
    #pragma unroll
    for (int nt = 0; nt < 2; ++nt) {
        int nloc = nt ? nloc1 : nloc0;
        float x = in[tau0 + nloc];
        #pragma unroll
        for (int mt = 0; mt < 4; ++mt) {
            int c0 = mt * 16 + quad * 4;
            f32x4 wv = *(const f32x4*)(w0v + c0);
            f32x4 bv = *(const f32x4*)(b0v + c0);
            #pragma unroll
            for (int r = 0; r < 4; ++r) hreg[mt][nt][r] = fmaf(wv[r], x, bv[r]);
            u64_t pk = pk4(hreg[mt][nt]);
            *HTW(0, nloc, mt, quad) = pk;
            if (nloc == 127) {
                ushort_t* dst = HB + (tau0 + 127) * 64 + c0;
                asm volatile("global_store_dwordx2 %0, %1, off sc1" :: "v"(dst), "v"(pk) : "memory");
            }
        }
    }
    asm volatile("s_waitcnt vmcnt(0)" ::: "memory");
    __syncthreads();
    if (tid == 0)
        __hip_atomic_store(&flags[blk << 5], 1u, __ATOMIC_RELAXED, __HIP_MEMORY_SCOPE_AGENT);

    f32x4 skip_acc[4][2];
    #pragma unroll
    for (int mt = 0; mt < 4; ++mt)
        #pragma unroll
        for (int nt = 0; nt < 2; ++nt)
            skip_acc[mt][nt] = (f32x4){0.0f, 0.0f, 0.0f, 0.0f};

    #pragma unroll 1
    for (int i = 0; i < NLAYERS; ++i) {
        const int cur = i & 1, nxt = cur ^ 1;
        const int d = 1 << (i >= 10 ? i - 10 : i);
        const int ip1 = i + 1;
        const int dnext = (ip1 < NLAYERS) ? (1 << (ip1 >= 10 ? ip1 - 10 : ip1)) : 0;
        const int hn = dnext > 128 ? 128 : dnext;      // rows to publish for next layer
        const int nleft = (d + 127) >> 7;              // producers needed (<=4)
        // anti-dep: buffer (i+1)%4 was last READ at layer i-3 by blocks b+k,
        // k <= ceil(d_{i-3}/128); they are done once flag >= (i-3)+2 = i-1.
        const int di3 = (i >= 3) ? (1 << ((i - 3) >= 10 ? i - 13 : i - 3)) : 0;
        const int nr3 = (di3 + 127) >> 7;
        const ushort_t* haloIn = HB + (unsigned)(i & 3) * HALO_USHORTS;
        ushort_t* haloOut = HB + (unsigned)((i + 1) & 3) * HALO_USHORTS;

        // ---- wait for neighbor progress (relaxed polls of LLC; no fences)
        if (w == 0) {
            int nb = -1; unsigned tgt = 0;
            if (l < 4) {
                int k = l + 1;
                if (k <= nleft) { nb = blk - k; tgt = (unsigned)(i + 1); }
            } else if (l < 8 && i >= 3 && i < NLAYERS - 1) {
                int k = l - 3;
                if (k <= nr3) { nb = blk + k; tgt = (unsigned)(i - 1); }
            }
            if (nb >= 0 && nb < NBLOCKS) {
                while (__hip_atomic_load(&flags[nb << 5], __ATOMIC_RELAXED,
                                         __HIP_MEMORY_SCOPE_AGENT) < tgt)
                    __builtin_amdgcn_s_sleep(1);
            }
        }
        __syncthreads();   // A: poll done; also orders prev-layer HT[cur] writes before reads

        const ushort_t* PW = pbf + i * PBF_PER_LAYER;
        const float* bfb = bf_all + i * 64;
        const float* bgb = bg_all + i * 64;
        const float* brb = br_all + i * 64;
        const float* bsb = bs_all + i * 64;

        // ---- gate B operands per tile: left from halo (bf16 global) or HT[cur];
        //      own from HT[cur]. Issue all global loads first, one waitcnt.
        int grow0 = tauN0 - d; if (grow0 < 0) grow0 = 0;
        int grow1 = tauN1 - d; if (grow1 < 0) grow1 = 0;
        bf16x8 bl[4][2];   // [ks][nt]; fully unrolled use => register-resident
        const bool hl0 = grow0 < tau0, hl1 = grow1 < tau0;
        if (hl0) {
            const ushort_t* hp = haloIn + grow0 * 64 + quad * 8;
            asm volatile(
                "global_load_dwordx4 %0, %2, off sc1\n\t"
                "global_load_dwordx4 %1, %2, off offset:64 sc1"
                : "=&v"(bl[0][0]), "=&v"(bl[1][0]) : "v"(hp) : "memory");
        }
        if (hl1) {
            const ushort_t* hp = haloIn + grow1 * 64 + quad * 8;
            asm volatile(
                "global_load_dwordx4 %0, %2, off sc1\n\t"
                "global_load_dwordx4 %1, %2, off offset:64 sc1"
                : "=&v"(bl[0][1]), "=&v"(bl[1][1]) : "v"(hp) : "memory");
        }
        if (!hl0) {
            int rl = grow0 - tau0;
            BF8 a0, a1; a0.u4 = *HTP(cur, rl, quad); a1.u4 = *HTP(cur, rl, 4 + quad);
            bl[0][0] = a0.v; bl[1][0] = a1.v;
        }
        if (!hl1) {
            int rl = grow1 - tau0;
            BF8 a0, a1; a0.u4 = *HTP(cur, rl, quad); a1.u4 = *HTP(cur, rl, 4 + quad);
            bl[0][1] = a0.v; bl[1][1] = a1.v;
        }
        {
            BF8 b0, b1, b2, b3;
            b0.u4 = *HTP(cur, nloc0, quad); b1.u4 = *HTP(cur, nloc0, 4 + quad);
            b2.u4 = *HTP(cur, nloc1, quad); b3.u4 = *HTP(cur, nloc1, 4 + quad);
            bl[2][0] = b0.v; bl[3][0] = b1.v;
            bl[2][1] = b2.v; bl[3][1] = b3.v;
        }
        asm volatile("s_waitcnt vmcnt(0) lgkmcnt(0)" ::: "memory");
        __builtin_amdgcn_sched_barrier(0);             // rule #18

        // ---- gates GEMM: each A-fragment load feeds BOTH tiles (the R13 point)
        f32x4 acc[8][2];
        #pragma unroll
        for (int mt = 0; mt < 4; ++mt) {
            f32x4 bfv = *(const f32x4*)(bfb + mt * 16 + quad * 4);
            f32x4 bgv = *(const f32x4*)(bgb + mt * 16 + quad * 4);
            acc[mt][0] = bfv; acc[mt][1] = bfv;
            acc[mt + 4][0] = bgv; acc[mt + 4][1] = bgv;
        }
        #pragma unroll
        for (int ks = 0; ks < 4; ++ks) {
            #pragma unroll
            for (int mt = 0; mt < 8; ++mt) {
                BF8 af; af.u4 = *(const uint4v*)(PW + (((mt << 2) + ks) * 64 + l) * 8);
                acc[mt][0] = __builtin_amdgcn_mfma_f32_16x16x32_bf16(af.v, bl[ks][0], acc[mt][0], 0, 0, 0);
                acc[mt][1] = __builtin_amdgcn_mfma_f32_16x16x32_bf16(af.v, bl[ks][1], acc[mt][1], 0, 0, 0);
            }
        }

        // ---- z = tanh(f)*sigmoid(g) -> ZB rows nloc0/nloc1 (wave-private)
        #pragma unroll
        for (int nt = 0; nt < 2; ++nt) {
            int nloc = nt ? nloc1 : nloc0;
            #pragma unroll
            for (int mt = 0; mt < 4; ++mt) {
                f32x4 z;
                #pragma unroll
                for (int r = 0; r < 4; ++r) {
                    float f = acc[mt][nt][r];
                    float g = acc[mt + 4][nt][r];
                    float e2 = __expf(2.0f * f);
                    float th = 1.0f - 2.0f * __builtin_amdgcn_rcpf(e2 + 1.0f);
                    float sg = __builtin_amdgcn_rcpf(1.0f + __expf(-g));
                    z[r] = th * sg;
                }
                *(u64_t*)(ZB + nloc * 72 + mt * 16 + quad * 4) = pk4(z);
            }
        }
        asm volatile("s_waitcnt lgkmcnt(0)" ::: "memory");
        __builtin_amdgcn_sched_barrier(0);

        // ---- res/skip GEMM, af shared across tiles
        f32x4 acc2[8][2];
        #pragma unroll
        for (int mt = 0; mt < 4; ++mt) {
            f32x4 brv = *(const f32x4*)(brb + mt * 16 + quad * 4);
            f32x4 bsv = *(const f32x4*)(bsb + mt * 16 + quad * 4);
            acc2[mt][0] = brv; acc2[mt][1] = brv;
            acc2[mt + 4][0] = bsv; acc2[mt + 4][1] = bsv;
        }
        const ushort_t* PRS = PW + 16384;
        #pragma unroll
        for (int ks = 0; ks < 2; ++ks) {
            BF8 t0, t1;
            t0.u4 = *(const uint4v*)(ZB + nloc0 * 72 + ks * 32 + quad * 8);
            t1.u4 = *(const uint4v*)(ZB + nloc1 * 72 + ks * 32 + quad * 8);
            #pragma unroll
            for (int mt = 0; mt < 8; ++mt) {
                BF8 af; af.u4 = *(const uint4v*)(PRS + (((mt << 1) + ks) * 64 + l) * 8);
                acc2[mt][0] = __builtin_amdgcn_mfma_f32_16x16x32_bf16(af.v, t0.v, acc2[mt][0], 0, 0, 0);
                acc2[mt][1] = __builtin_amdgcn_mfma_f32_16x16x32_bf16(af.v, t1.v, acc2[mt][1], 0, 0, 0);
            }
        }

        // ---- epilogue: hreg = res + right (fp32 regs); bf16 -> HT[nxt] (+ halo)
        #pragma unroll
        for (int nt = 0; nt < 2; ++nt) {
            #pragma unroll
            for (int mt = 0; mt < 4; ++mt) {
                #pragma unroll
                for (int r = 0; r < 4; ++r) {
                    hreg[mt][nt][r] = acc2[mt][nt][r] + hreg[mt][nt][r];
                    skip_acc[mt][nt][r] += acc2[mt + 4][nt][r];
                }
            }
        }
        if (i < NLAYERS - 1) {
            #pragma unroll
            for (int nt = 0; nt < 2; ++nt) {
                int nloc = nt ? nloc1 : nloc0;
                #pragma unroll
                for (int mt = 0; mt < 4; ++mt) {
                    u64_t pk = pk4(hreg[mt][nt]);
                    *HTW(nxt, nloc, mt, quad) = pk;
                    if (nloc >= 128 - hn) {
                        ushort_t* dst = haloOut + (tau0 + nloc) * 64 + mt * 16 + quad * 4;
                        asm volatile("global_store_dwordx2 %0, %1, off sc1"
                                     :: "v"(dst), "v"(pk) : "memory");
                    }
                }
            }
        }

        // ---- publish layer completion (halo at LLC after vmcnt + barrier)
        asm volatile("s_waitcnt vmcnt(0)" ::: "memory");
        __syncthreads();   // C: all waves' halo stores drained; HT[nxt] writes visible
        if (i < NLAYERS - 1 && tid == 0)
            __hip_atomic_store(&flags[blk << 5], (unsigned)(i + 2), __ATOMIC_RELAXED,
                               __HIP_MEMORY_SCOPE_AGENT);
    }

    // ---- output head (block-local; skip in regs; ZB rows wave-private)
    asm volatile("s_waitcnt lgkmcnt(0)" ::: "memory");   // last layer's ZB reads done
    #pragma unroll
    for (int nt = 0; nt < 2; ++nt) {
        int nloc = nt ? nloc1 : nloc0;
        #pragma unroll
        for (int mt = 0; mt < 4; ++mt) {
            f32x4 a = *(const f32x4*)(alpha + mt * 16 + quad * 4);
            f32x4 y;
            #pragma unroll
            for (int r = 0; r < 4; ++r) {
                float x = skip_acc[mt][nt][r];
                y[r] = x > 0.0f ? x : a[r] * x;
            }
            *(u64_t*)(ZB + nloc * 72 + mt * 16 + quad * 4) = pk4(y);
        }
    }
    asm volatile("s_waitcnt lgkmcnt(0)" ::: "memory");
    __builtin_amdgcn_sched_barrier(0);

    const ushort_t* PW0 = pbf + PBF_LAYERS;
    const ushort_t* PW1 = PW0 + 4096;

    // W0 GEMM (64x64), af shared across tiles
    f32x4 acc0[4][2];
    #pragma unroll
    for (int mt = 0; mt < 4; ++mt) {
        f32x4 b = *(const f32x4*)(b_out0 + mt * 16 + quad * 4);
        acc0[mt][0] = b; acc0[mt][1] = b;
    }
    #pragma unroll
    for (int ks = 0; ks < 2; ++ks) {
        BF8 t0, t1;
        t0.u4 = *(const uint4v*)(ZB + nloc0 * 72 + ks * 32 + quad * 8);
        t1.u4 = *(const uint4v*)(ZB + nloc1 * 72 + ks * 32 + quad * 8);
        #pragma unroll
        for (int mt = 0; mt < 4; ++mt) {
            BF8 af; af.u4 = *(const uint4v*)(PW0 + (((mt << 1) + ks) * 64 + l) * 8);
            acc0[mt][0] = __builtin_amdgcn_mfma_f32_16x16x32_bf16(af.v, t0.v, acc0[mt][0], 0, 0, 0);
            acc0[mt][1] = __builtin_amdgcn_mfma_f32_16x16x32_bf16(af.v, t1.v, acc0[mt][1], 0, 0, 0);
        }
    }
    asm volatile("s_waitcnt lgkmcnt(0)" ::: "memory");   // W0 reads done before overwrite

    // lrelu_alpha1 -> X1 back into ZB (wave-private rows)
    #pragma unroll
    for (int nt = 0; nt < 2; ++nt) {
        int nloc = nt ? nloc1 : nloc0;
        #pragma unroll
        for (int mt = 0; mt < 4; ++mt) {
            f32x4 a = *(const f32x4*)(alpha + 64 + mt * 16 + quad * 4);
            f32x4 y;
            #pragma unroll
            for (int r = 0; r < 4; ++r) {
                float x = acc0[mt][nt][r];
                y[r] = x > 0.0f ? x : a[r] * x;
            }
            *(u64_t*)(ZB + nloc * 72 + mt * 16 + quad * 4) = pk4(y);
        }
    }
    asm volatile("s_waitcnt lgkmcnt(0)" ::: "memory");
    __builtin_amdgcn_sched_barrier(0);

    // W1 GEMM (256x64), af shared across tiles
    f32x4 acc1[16][2];
    #pragma unroll
    for (int mt = 0; mt < 16; ++mt) {
        f32x4 b = *(const f32x4*)(b_out1 + mt * 16 + quad * 4);
        acc1[mt][0] = b; acc1[mt][1] = b;
    }
    #pragma unroll
    for (int ks = 0; ks < 2; ++ks) {
        BF8 t0, t1;
        t0.u4 = *(const uint4v*)(ZB + nloc0 * 72 + ks * 32 + quad * 8);
        t1.u4 = *(const uint4v*)(ZB + nloc1 * 72 + ks * 32 + quad * 8);
        #pragma unroll
        for (int mt = 0; mt < 16; ++mt) {
            BF8 af; af.u4 = *(const uint4v*)(PW1 + (((mt << 1) + ks) * 64 + l) * 8);
            acc1[mt][0] = __builtin_amdgcn_mfma_f32_16x16x32_bf16(af.v, t0.v, acc1[mt][0], 0, 0, 0);
            acc1[mt][1] = __builtin_amdgcn_mfma_f32_16x16x32_bf16(af.v, t1.v, acc1[mt][1], 0, 0, 0);
        }
    }

    #pragma unroll
    for (int nt = 0; nt < 2; ++nt) {
        int nloc = nt ? nloc1 : nloc0;
        int u = tau0 + nloc - OUT_START;
        if (u >= 0) {
            #pragma unroll
            for (int mt = 0; mt < 16; ++mt)
                #pragma unroll
                for (int r = 0; r < 4; ++r)
                    out[(mt * 16 + quad * 4 + r) * OUT_W + u] = acc1[mt][nt][r];
        }
    }
#undef HTP
#undef HTW
}

// ---------------------------------------------------------------- launch
extern "C" void kernel_launch(void* const* d_in, const int* in_sizes, int n_in,
                              void* d_out, int out_size, void* d_ws, size_t ws_size,
                              hipStream_t stream)
{
    const float* input  = (const float*)d_in[0];
    const float* w0     = (const float*)d_in[1];
    const float* b0     = (const float*)d_in[2];
    const float* wf     = (const float*)d_in[3];
    const float* bf     = (const float*)d_in[4];
    const float* wg     = (const float*)d_in[5];
    const float* bg     = (const float*)d_in[6];
    const float* wr     = (const float*)d_in[7];
    const float* br     = (const float*)d_in[8];
    const float* wsk    = (const float*)d_in[9];
    const float* bs     = (const float*)d_in[10];
    const float* alpha  = (const float*)d_in[11];
    const float* w_out0 = (const float*)d_in[12];
    const float* b_out0 = (const float*)d_in[13];
    const float* w_out1 = (const float*)d_in[14];
    const float* b_out1 = (const float*)d_in[15];
    float* outp = (float*)d_out;

    float* wsbase = (float*)d_ws;
    ushort_t* pbf = (ushort_t*)wsbase;
    ushort_t* HB = (ushort_t*)(wsbase + HALO_OFF);
    unsigned* flags = (unsigned*)(wsbase + FLAG_OFF);

    pack_mfma<<<PBF_TOTAL / 256, 256, 0, stream>>>(wf, wg, wr, wsk, w_out0, w_out1, pbf, flags);

    wavenet_fused<<<dim3(NBLOCKS), dim3(256), 0, stream>>>(
        input, w0, b0, pbf, bf, bg, br, bs, alpha, b_out0, b_out1,
        HB, outp, flags);
}

// Round 14
// 321.101 us; speedup vs baseline: 1.8835x; 1.1883x over previous
//
#include <hip/hip_runtime.h>

typedef unsigned short ushort_t;
typedef unsigned long long u64_t;
typedef __attribute__((ext_vector_type(8))) __bf16 bf16x8;
typedef __attribute__((ext_vector_type(4))) __bf16 bf16x4;
typedef __attribute__((ext_vector_type(4))) float f32x4;
typedef __attribute__((ext_vector_type(4))) unsigned int uint4v;

#define T_TOTAL 65536
#define NLAYERS 20
#define OUT_START 2047
#define OUT_W 63489
#define NBLOCKS 512

// workspace layout (floats)
#define PBF_PER_LAYER 24576
#define PBF_LAYERS (NLAYERS * PBF_PER_LAYER)        // 491520 ushorts
#define PBF_TOTAL (PBF_LAYERS + 4096 + 16384)       // 512000 ushorts
#define HALO_OFF 524288                              // float offset of halo ring
#define HALO_USHORTS (T_TOTAL * 64)                  // one bf16 halo buffer = 8 MB
#define HALO_FLOATS (HALO_USHORTS / 2)
#define FLAG_OFF (HALO_OFF + 4 * HALO_FLOATS)        // 512 flags, 128B apart

__device__ __forceinline__ ushort_t f2bf(float x) {
    union { float f; unsigned u; } c; c.f = x;
    unsigned u = c.u + 0x7FFFu + ((c.u >> 16) & 1u);   // RNE
    return (ushort_t)(u >> 16);
}

union BF8 { uint4v u4; bf16x8 v; };

// HW bf16 pack (compiler emits v_cvt_pk_bf16_f32, RNE)
__device__ __forceinline__ u64_t pk4(f32x4 v) {
    union { bf16x4 b; u64_t u; } r;
    r.b[0] = (__bf16)v[0]; r.b[1] = (__bf16)v[1];
    r.b[2] = (__bf16)v[2]; r.b[3] = (__bf16)v[3];
    return r.u;
}

// ---------------------------------------------------------------- pack ALL MFMA weights (bf16, A-fragment order)
__global__ __launch_bounds__(256) void pack_mfma(
    const float* __restrict__ wf, const float* __restrict__ wg,
    const float* __restrict__ wr, const float* __restrict__ wsk,
    const float* __restrict__ w0h, const float* __restrict__ w1h,
    ushort_t* __restrict__ out, unsigned* __restrict__ flags)
{
    int idx = blockIdx.x * 256 + threadIdx.x;
    if (idx < NBLOCKS) flags[idx << 5] = 0u;   // reset progress flags every launch (replay-safe)
    if (idx >= PBF_TOTAL) return;
    float v;
    if (idx < PBF_LAYERS) {
        int i = idx / PBF_PER_LAYER;
        int r = idx - i * PBF_PER_LAYER;
        if (r < 16384) {                  // gates A (128x128 = [f;g] x [left||right])
            int j = r & 7, l = (r >> 3) & 63, ks = (r >> 9) & 3, mt = r >> 11;
            int m = mt * 16 + (l & 15);
            int k = ks * 32 + ((l >> 4) << 3) + j;
            int o = m & 63, c = k & 63, half = k >> 6;
            const float* src = (m < 64) ? wf : wg;
            v = src[(((i * 64 + o) * 64 + c) << 1) + half];
        } else {                          // rs A (128x64 = [r;s] x c)
            int rr = r - 16384;
            int j = rr & 7, l = (rr >> 3) & 63, ks = (rr >> 9) & 1, mt = rr >> 10;
            int m = mt * 16 + (l & 15);
            int k = ks * 32 + ((l >> 4) << 3) + j;
            v = (m < 64) ? wr[(i * 64 + m) * 64 + k] : wsk[(i * 64 + (m - 64)) * 64 + k];
        }
    } else if (idx < PBF_LAYERS + 4096) { // W0 head (64x64)
        int rr = idx - PBF_LAYERS;
        int j = rr & 7, l = (rr >> 3) & 63, ks = (rr >> 9) & 1, mt = rr >> 10;
        int m = mt * 16 + (l & 15);
        int k = ks * 32 + ((l >> 4) << 3) + j;
        v = w0h[m * 64 + k];
    } else {                              // W1 head (256x64)
        int rr = idx - PBF_LAYERS - 4096;
        int j = rr & 7, l = (rr >> 3) & 63, ks = (rr >> 9) & 1, mt = rr >> 10;
        int m = mt * 16 + (l & 15);
        int k = ks * 32 + ((l >> 4) << 3) + j;
        v = w1h[m * 64 + k];
    }
    out[idx] = f2bf(v);
}

// ---------------------------------------------------------------- fused persistent kernel
// R14 (on R13, fused ~286us; weight-stream theory CONFIRMED by R13's -25%):
// stage the 32KB GATES panel into LDS once per block per layer; all 4 waves
// read A-fragments from LDS (contiguous 64x16B ds_read_b128) instead of 4x
// redundant L2 streams. Per-CU weight traffic 384 -> 192 KB/layer; gates
// operand latency ~200cy (L2) -> ~12cy (LDS).
// LDS budget (64KB static limit, 2 blocks/CU): WG 32KB (gates panel; ZB z-
// staging ALIASED into it — z writes start only after all af reads, enforced
// by barrier B2) + HT 16KB SINGLE-buffered (barrier B separates all waves'
// HT reads from epilogue writes) = 48KB/block.
// Barriers: A (post-poll), B (operands+staging done), B2 (af reads done,
// pre-ZB-write), C (pre-flag). R10 showed barrier-count deltas are ~free.
// Everything else identical to R13 (2-tile/wave af sharing, fp32 residual in
// regs, rcp activations, 4-deep halo ring, fence-free sc1/LLC, relaxed flags).
__global__ __launch_bounds__(256, 2) void wavenet_fused(
    const float* __restrict__ in, const float* __restrict__ w0v, const float* __restrict__ b0v,
    const ushort_t* __restrict__ pbf,
    const float* __restrict__ bf_all, const float* __restrict__ bg_all,
    const float* __restrict__ br_all, const float* __restrict__ bs_all,
    const float* __restrict__ alpha, const float* __restrict__ b_out0,
    const float* __restrict__ b_out1,
    ushort_t* __restrict__ HB, float* __restrict__ out, unsigned* flags)
{
    __shared__ alignas(16) ushort_t WG[16384];      // 32 KB gates panel (ZB aliased)
    __shared__ alignas(16) ushort_t HT[128 * 64];   // 16 KB bf16 H, single-buffered

    ushort_t* const ZB = WG;                        // z staging aliases WG (9216 <= 16384)

    const int tid = threadIdx.x;
    const int l = tid & 63, w = tid >> 6;          // 4 waves
    const int l15 = l & 15, quad = l >> 4;
    const int bid = (int)blockIdx.x;
    const int blk = (bid & 7) * 64 + (bid >> 3);   // XCD-chunked swizzle
    const int tau0 = blk * 128;
    const int nloc0 = w * 32 + l15;                // wave's tile 0 row (0..127)
    const int nloc1 = nloc0 + 16;                  // wave's tile 1 row
    const int tauN0 = tau0 + nloc0;
    const int tauN1 = tau0 + nloc1;

// 16B bf16 granule g (0..7) of row r, XOR-swizzled by row (single HT buffer)
#define HTP(r, g) ((const uint4v*)((char*)HT + ((r) << 7) + ((((g) ^ ((r) & 7))) << 4)))
// u64 write slot for ch chunk mt*16+quad*4 of row r
#define HTW(r, mt, q) ((u64_t*)((char*)HT + ((r) << 7) + ((((2 * (mt) + ((q) >> 1)) ^ ((r) & 7))) << 4) + (((q) & 1) << 3)))

    // ---- init: thread owns rows nloc0/nloc1, ch chunks mt*16+quad*4; fp32 in
    //      hreg, bf16 into HT; row 127 published to halo ring buffer 0 (d_0=1)
    f32x4 hreg[4][2];
    #pragma unroll
    for (int nt = 0; nt < 2; ++nt) {
        int nloc = nt ? nloc1 : nloc0;
        float x = in[tau0 + nloc];
        #pragma unroll
        for (int mt = 0; mt < 4; ++mt) {
            int c0 = mt * 16 + quad * 4;
            f32x4 wv = *(const f32x4*)(w0v + c0);
            f32x4 bv = *(const f32x4*)(b0v + c0);
            #pragma unroll
            for (int r = 0; r < 4; ++r) hreg[mt][nt][r] = fmaf(wv[r], x, bv[r]);
            u64_t pk = pk4(hreg[mt][nt]);
            *HTW(nloc, mt, quad) = pk;
            if (nloc == 127) {
                ushort_t* dst = HB + (tau0 + 127) * 64 + c0;
                asm volatile("global_store_dwordx2 %0, %1, off sc1" :: "v"(dst), "v"(pk) : "memory");
            }
        }
    }
    asm volatile("s_waitcnt vmcnt(0)" ::: "memory");
    __syncthreads();
    if (tid == 0)
        __hip_atomic_store(&flags[blk << 5], 1u, __ATOMIC_RELAXED, __HIP_MEMORY_SCOPE_AGENT);

    f32x4 skip_acc[4][2];
    #pragma unroll
    for (int mt = 0; mt < 4; ++mt)
        #pragma unroll
        for (int nt = 0; nt < 2; ++nt)
            skip_acc[mt][nt] = (f32x4){0.0f, 0.0f, 0.0f, 0.0f};

    #pragma unroll 1
    for (int i = 0; i < NLAYERS; ++i) {
        const int d = 1 << (i >= 10 ? i - 10 : i);
        const int ip1 = i + 1;
        const int dnext = (ip1 < NLAYERS) ? (1 << (ip1 >= 10 ? ip1 - 10 : ip1)) : 0;
        const int hn = dnext > 128 ? 128 : dnext;      // rows to publish for next layer
        const int nleft = (d + 127) >> 7;              // producers needed (<=4)
        // anti-dep: buffer (i+1)%4 was last READ at layer i-3 by blocks b+k,
        // k <= ceil(d_{i-3}/128); they are done once flag >= (i-3)+2 = i-1.
        const int di3 = (i >= 3) ? (1 << ((i - 3) >= 10 ? i - 13 : i - 3)) : 0;
        const int nr3 = (di3 + 127) >> 7;
        const ushort_t* haloIn = HB + (unsigned)(i & 3) * HALO_USHORTS;
        ushort_t* haloOut = HB + (unsigned)((i + 1) & 3) * HALO_USHORTS;

        // ---- wait for neighbor progress (relaxed polls of LLC; no fences)
        if (w == 0) {
            int nb = -1; unsigned tgt = 0;
            if (l < 4) {
                int k = l + 1;
                if (k <= nleft) { nb = blk - k; tgt = (unsigned)(i + 1); }
            } else if (l < 8 && i >= 3 && i < NLAYERS - 1) {
                int k = l - 3;
                if (k <= nr3) { nb = blk + k; tgt = (unsigned)(i - 1); }
            }
            if (nb >= 0 && nb < NBLOCKS) {
                while (__hip_atomic_load(&flags[nb << 5], __ATOMIC_RELAXED,
                                         __HIP_MEMORY_SCOPE_AGENT) < tgt)
                    __builtin_amdgcn_s_sleep(1);
            }
        }
        __syncthreads();   // A: poll done; prev-layer HT writes + ZB reads ordered

        const ushort_t* PW = pbf + i * PBF_PER_LAYER;
        const float* bfb = bf_all + i * 64;
        const float* bgb = bg_all + i * 64;
        const float* brb = br_all + i * 64;
        const float* bsb = bs_all + i * 64;

        // ---- stage gates panel (32KB) into WG: wave w copies its 8KB chunk
        {
            const char* gsrc = (const char*)PW + (w << 13);
            char* ldst = (char*)WG + (w << 13);
            #pragma unroll
            for (int r = 0; r < 8; ++r)
                *(uint4v*)(ldst + (r << 10) + (l << 4)) =
                    *(const uint4v*)(gsrc + (r << 10) + (l << 4));
        }

        // ---- gate B operands per tile: left from halo (bf16 global) or HT;
        //      own from HT. Issue all global loads first, one waitcnt.
        int grow0 = tauN0 - d; if (grow0 < 0) grow0 = 0;
        int grow1 = tauN1 - d; if (grow1 < 0) grow1 = 0;
        bf16x8 bl[4][2];   // [ks][nt]; fully unrolled use => register-resident
        const bool hl0 = grow0 < tau0, hl1 = grow1 < tau0;
        if (hl0) {
            const ushort_t* hp = haloIn + grow0 * 64 + quad * 8;
            asm volatile(
                "global_load_dwordx4 %0, %2, off sc1\n\t"
                "global_load_dwordx4 %1, %2, off offset:64 sc1"
                : "=&v"(bl[0][0]), "=&v"(bl[1][0]) : "v"(hp) : "memory");
        }
        if (hl1) {
            const ushort_t* hp = haloIn + grow1 * 64 + quad * 8;
            asm volatile(
                "global_load_dwordx4 %0, %2, off sc1\n\t"
                "global_load_dwordx4 %1, %2, off offset:64 sc1"
                : "=&v"(bl[0][1]), "=&v"(bl[1][1]) : "v"(hp) : "memory");
        }
        if (!hl0) {
            int rl = grow0 - tau0;
            BF8 a0, a1; a0.u4 = *HTP(rl, quad); a1.u4 = *HTP(rl, 4 + quad);
            bl[0][0] = a0.v; bl[1][0] = a1.v;
        }
        if (!hl1) {
            int rl = grow1 - tau0;
            BF8 a0, a1; a0.u4 = *HTP(rl, quad); a1.u4 = *HTP(rl, 4 + quad);
            bl[0][1] = a0.v; bl[1][1] = a1.v;
        }
        {
            BF8 b0, b1, b2, b3;
            b0.u4 = *HTP(nloc0, quad); b1.u4 = *HTP(nloc0, 4 + quad);
            b2.u4 = *HTP(nloc1, quad); b3.u4 = *HTP(nloc1, 4 + quad);
            bl[2][0] = b0.v; bl[3][0] = b1.v;
            bl[2][1] = b2.v; bl[3][1] = b3.v;
        }
        asm volatile("s_waitcnt vmcnt(0) lgkmcnt(0)" ::: "memory");
        __builtin_amdgcn_sched_barrier(0);             // rule #18
        __syncthreads();   // B: staging ds_writes + all waves' HT reads done

        // ---- gates GEMM: af from LDS (WG), each load feeds BOTH tiles
        f32x4 acc[8][2];
        #pragma unroll
        for (int mt = 0; mt < 4; ++mt) {
            f32x4 bfv = *(const f32x4*)(bfb + mt * 16 + quad * 4);
            f32x4 bgv = *(const f32x4*)(bgb + mt * 16 + quad * 4);
            acc[mt][0] = bfv; acc[mt][1] = bfv;
            acc[mt + 4][0] = bgv; acc[mt + 4][1] = bgv;
        }
        #pragma unroll
        for (int ks = 0; ks < 4; ++ks) {
            #pragma unroll
            for (int mt = 0; mt < 8; ++mt) {
                BF8 af; af.u4 = *(const uint4v*)((const char*)WG + ((((mt << 2) + ks) * 64 + l) << 4));
                acc[mt][0] = __builtin_amdgcn_mfma_f32_16x16x32_bf16(af.v, bl[ks][0], acc[mt][0], 0, 0, 0);
                acc[mt][1] = __builtin_amdgcn_mfma_f32_16x16x32_bf16(af.v, bl[ks][1], acc[mt][1], 0, 0, 0);
            }
        }
        __syncthreads();   // B2: all waves' af reads done before ZB(=WG) overwrite

        // ---- z = tanh(f)*sigmoid(g) -> ZB rows nloc0/nloc1 (wave-private)
        #pragma unroll
        for (int nt = 0; nt < 2; ++nt) {
            int nloc = nt ? nloc1 : nloc0;
            #pragma unroll
            for (int mt = 0; mt < 4; ++mt) {
                f32x4 z;
                #pragma unroll
                for (int r = 0; r < 4; ++r) {
                    float f = acc[mt][nt][r];
                    float g = acc[mt + 4][nt][r];
                    float e2 = __expf(2.0f * f);
                    float th = 1.0f - 2.0f * __builtin_amdgcn_rcpf(e2 + 1.0f);
                    float sg = __builtin_amdgcn_rcpf(1.0f + __expf(-g));
                    z[r] = th * sg;
                }
                *(u64_t*)(ZB + nloc * 72 + mt * 16 + quad * 4) = pk4(z);
            }
        }
        asm volatile("s_waitcnt lgkmcnt(0)" ::: "memory");
        __builtin_amdgcn_sched_barrier(0);

        // ---- res/skip GEMM, af from global (PRS), shared across tiles
        f32x4 acc2[8][2];
        #pragma unroll
        for (int mt = 0; mt < 4; ++mt) {
            f32x4 brv = *(const f32x4*)(brb + mt * 16 + quad * 4);
            f32x4 bsv = *(const f32x4*)(bsb + mt * 16 + quad * 4);
            acc2[mt][0] = brv; acc2[mt][1] = brv;
            acc2[mt + 4][0] = bsv; acc2[mt + 4][1] = bsv;
        }
        const ushort_t* PRS = PW + 16384;
        #pragma unroll
        for (int ks = 0; ks < 2; ++ks) {
            BF8 t0, t1;
            t0.u4 = *(const uint4v*)(ZB + nloc0 * 72 + ks * 32 + quad * 8);
            t1.u4 = *(const uint4v*)(ZB + nloc1 * 72 + ks * 32 + quad * 8);
            #pragma unroll
            for (int mt = 0; mt < 8; ++mt) {
                BF8 af; af.u4 = *(const uint4v*)(PRS + (((mt << 1) + ks) * 64 + l) * 8);
                acc2[mt][0] = __builtin_amdgcn_mfma_f32_16x16x32_bf16(af.v, t0.v, acc2[mt][0], 0, 0, 0);
                acc2[mt][1] = __builtin_amdgcn_mfma_f32_16x16x32_bf16(af.v, t1.v, acc2[mt][1], 0, 0, 0);
            }
        }

        // ---- epilogue: hreg = res + right (fp32 regs); bf16 -> HT (+ halo)
        #pragma unroll
        for (int nt = 0; nt < 2; ++nt) {
            #pragma unroll
            for (int mt = 0; mt < 4; ++mt) {
                #pragma unroll
                for (int r = 0; r < 4; ++r) {
                    hreg[mt][nt][r] = acc2[mt][nt][r] + hreg[mt][nt][r];
                    skip_acc[mt][nt][r] += acc2[mt + 4][nt][r];
                }
            }
        }
        if (i < NLAYERS - 1) {
            #pragma unroll
            for (int nt = 0; nt < 2; ++nt) {
                int nloc = nt ? nloc1 : nloc0;
                #pragma unroll
                for (int mt = 0; mt < 4; ++mt) {
                    u64_t pk = pk4(hreg[mt][nt]);
                    *HTW(nloc, mt, quad) = pk;
                    if (nloc >= 128 - hn) {
                        ushort_t* dst = haloOut + (tau0 + nloc) * 64 + mt * 16 + quad * 4;
                        asm volatile("global_store_dwordx2 %0, %1, off sc1"
                                     :: "v"(dst), "v"(pk) : "memory");
                    }
                }
            }
        }

        // ---- publish layer completion (halo at LLC after vmcnt + barrier)
        asm volatile("s_waitcnt vmcnt(0)" ::: "memory");
        __syncthreads();   // C: all waves' halo stores drained; HT writes visible
        if (i < NLAYERS - 1 && tid == 0)
            __hip_atomic_store(&flags[blk << 5], (unsigned)(i + 2), __ATOMIC_RELAXED,
                               __HIP_MEMORY_SCOPE_AGENT);
    }

    // ---- output head (block-local; skip in regs; ZB rows wave-private)
    asm volatile("s_waitcnt lgkmcnt(0)" ::: "memory");   // last layer's ZB reads done
    #pragma unroll
    for (int nt = 0; nt < 2; ++nt) {
        int nloc = nt ? nloc1 : nloc0;
        #pragma unroll
        for (int mt = 0; mt < 4; ++mt) {
            f32x4 a = *(const f32x4*)(alpha + mt * 16 + quad * 4);
            f32x4 y;
            #pragma unroll
            for (int r = 0; r < 4; ++r) {
                float x = skip_acc[mt][nt][r];
                y[r] = x > 0.0f ? x : a[r] * x;
            }
            *(u64_t*)(ZB + nloc * 72 + mt * 16 + quad * 4) = pk4(y);
        }
    }
    asm volatile("s_waitcnt lgkmcnt(0)" ::: "memory");
    __builtin_amdgcn_sched_barrier(0);

    const ushort_t* PW0 = pbf + PBF_LAYERS;
    const ushort_t* PW1 = PW0 + 4096;

    // W0 GEMM (64x64), af shared across tiles
    f32x4 acc0[4][2];
    #pragma unroll
    for (int mt = 0; mt < 4; ++mt) {
        f32x4 b = *(const f32x4*)(b_out0 + mt * 16 + quad * 4);
        acc0[mt][0] = b; acc0[mt][1] = b;
    }
    #pragma unroll
    for (int ks = 0; ks < 2; ++ks) {
        BF8 t0, t1;
        t0.u4 = *(const uint4v*)(ZB + nloc0 * 72 + ks * 32 + quad * 8);
        t1.u4 = *(const uint4v*)(ZB + nloc1 * 72 + ks * 32 + quad * 8);
        #pragma unroll
        for (int mt = 0; mt < 4; ++mt) {
            BF8 af; af.u4 = *(const uint4v*)(PW0 + (((mt << 1) + ks) * 64 + l) * 8);
            acc0[mt][0] = __builtin_amdgcn_mfma_f32_16x16x32_bf16(af.v, t0.v, acc0[mt][0], 0, 0, 0);
            acc0[mt][1] = __builtin_amdgcn_mfma_f32_16x16x32_bf16(af.v, t1.v, acc0[mt][1], 0, 0, 0);
        }
    }
    asm volatile("s_waitcnt lgkmcnt(0)" ::: "memory");   // W0 reads done before overwrite

    // lrelu_alpha1 -> X1 back into ZB (wave-private rows)
    #pragma unroll
    for (int nt = 0; nt < 2; ++nt) {
        int nloc = nt ? nloc1 : nloc0;
        #pragma unroll
        for (int mt = 0; mt < 4; ++mt) {
            f32x4 a = *(const f32x4*)(alpha + 64 + mt * 16 + quad * 4);
            f32x4 y;
            #pragma unroll
            for (int r = 0; r < 4; ++r) {
                float x = acc0[mt][nt][r];
                y[r] = x > 0.0f ? x : a[r] * x;
            }
            *(u64_t*)(ZB + nloc * 72 + mt * 16 + quad * 4) = pk4(y);
        }
    }
    asm volatile("s_waitcnt lgkmcnt(0)" ::: "memory");
    __builtin_amdgcn_sched_barrier(0);

    // W1 GEMM (256x64), af shared across tiles
    f32x4 acc1[16][2];
    #pragma unroll
    for (int mt = 0; mt < 16; ++mt) {
        f32x4 b = *(const f32x4*)(b_out1 + mt * 16 + quad * 4);
        acc1[mt][0] = b; acc1[mt][1] = b;
    }
    #pragma unroll
    for (int ks = 0; ks < 2; ++ks) {
        BF8 t0, t1;
        t0.u4 = *(const uint4v*)(ZB + nloc0 * 72 + ks * 32 + quad * 8);
        t1.u4 = *(const uint4v*)(ZB + nloc1 * 72 + ks * 32 + quad * 8);
        #pragma unroll
        for (int mt = 0; mt < 16; ++mt) {
            BF8 af; af.u4 = *(const uint4v*)(PW1 + (((mt << 1) + ks) * 64 + l) * 8);
            acc1[mt][0] = __builtin_amdgcn_mfma_f32_16x16x32_bf16(af.v, t0.v, acc1[mt][0], 0, 0, 0);
            acc1[mt][1] = __builtin_amdgcn_mfma_f32_16x16x32_bf16(af.v, t1.v, acc1[mt][1], 0, 0, 0);
        }
    }

    #pragma unroll
    for (int nt = 0; nt < 2; ++nt) {
        int nloc = nt ? nloc1 : nloc0;
        int u = tau0 + nloc - OUT_START;
        if (u >= 0) {
            #pragma unroll
            for (int mt = 0; mt < 16; ++mt)
                #pragma unroll
                for (int r = 0; r < 4; ++r)
                    out[(mt * 16 + quad * 4 + r) * OUT_W + u] = acc1[mt][nt][r];
        }
    }
#undef HTP
#undef HTW
}

// ---------------------------------------------------------------- launch
extern "C" void kernel_launch(void* const* d_in, const int* in_sizes, int n_in,
                              void* d_out, int out_size, void* d_ws, size_t ws_size,
                              hipStream_t stream)
{
    const float* input  = (const float*)d_in[0];
    const float* w0     = (const float*)d_in[1];
    const float* b0     = (const float*)d_in[2];
    const float* wf     = (const float*)d_in[3];
    const float* bf     = (const float*)d_in[4];
    const float* wg     = (const float*)d_in[5];
    const float* bg     = (const float*)d_in[6];
    const float* wr     = (const float*)d_in[7];
    const float* br     = (const float*)d_in[8];
    const float* wsk    = (const float*)d_in[9];
    const float* bs     = (const float*)d_in[10];
    const float* alpha  = (const float*)d_in[11];
    const float* w_out0 = (const float*)d_in[12];
    const float* b_out0 = (const float*)d_in[13];
    const float* w_out1 = (const float*)d_in[14];
    const float* b_out1 = (const float*)d_in[15];
    float* outp = (float*)d_out;

    float* wsbase = (float*)d_ws;
    ushort_t* pbf = (ushort_t*)wsbase;
    ushort_t* HB = (ushort_t*)(wsbase + HALO_OFF);
    unsigned* flags = (unsigned*)(wsbase + FLAG_OFF);

    pack_mfma<<<PBF_TOTAL / 256, 256, 0, stream>>>(wf, wg, wr, wsk, w_out0, w_out1, pbf, flags);

    wavenet_fused<<<dim3(NBLOCKS), dim3(256), 0, stream>>>(
        input, w0, b0, pbf, bf, bg, br, bs, alpha, b_out0, b_out1,
        HB, outp, flags);
}

// Round 15
// 253.329 us; speedup vs baseline: 2.3874x; 1.2675x over previous
//
#include <hip/hip_runtime.h>

typedef unsigned short ushort_t;
typedef unsigned long long u64_t;
typedef __attribute__((ext_vector_type(8))) __bf16 bf16x8;
typedef __attribute__((ext_vector_type(4))) __bf16 bf16x4;
typedef __attribute__((ext_vector_type(4))) float f32x4;
typedef __attribute__((ext_vector_type(4))) unsigned int uint4v;

#define T_TOTAL 65536
#define NLAYERS 20
#define OUT_START 2047
#define OUT_W 63489
#define NBLOCKS 512

// workspace layout (floats)
#define PBF_PER_LAYER 24576
#define PBF_LAYERS (NLAYERS * PBF_PER_LAYER)        // 491520 ushorts
#define PBF_TOTAL (PBF_LAYERS + 4096 + 16384)       // 512000 ushorts
#define HALO_OFF 524288                              // float offset of halo ring
#define HALO_USHORTS (T_TOTAL * 64)                  // one bf16 halo buffer = 8 MB
#define HALO_FLOATS (HALO_USHORTS / 2)
#define FLAG_OFF (HALO_OFF + 4 * HALO_FLOATS)        // 512 flags, 128B apart

__device__ __forceinline__ ushort_t f2bf(float x) {
    union { float f; unsigned u; } c; c.f = x;
    unsigned u = c.u + 0x7FFFu + ((c.u >> 16) & 1u);   // RNE
    return (ushort_t)(u >> 16);
}

union BF8 { uint4v u4; bf16x8 v; };

// HW bf16 pack (compiler emits v_cvt_pk_bf16_f32, RNE)
__device__ __forceinline__ u64_t pk4(f32x4 v) {
    union { bf16x4 b; u64_t u; } r;
    r.b[0] = (__bf16)v[0]; r.b[1] = (__bf16)v[1];
    r.b[2] = (__bf16)v[2]; r.b[3] = (__bf16)v[3];
    return r.u;
}

// ---------------------------------------------------------------- pack ALL MFMA weights (bf16, A-fragment order)
__global__ __launch_bounds__(256) void pack_mfma(
    const float* __restrict__ wf, const float* __restrict__ wg,
    const float* __restrict__ wr, const float* __restrict__ wsk,
    const float* __restrict__ w0h, const float* __restrict__ w1h,
    ushort_t* __restrict__ out, unsigned* __restrict__ flags)
{
    int idx = blockIdx.x * 256 + threadIdx.x;
    if (idx < NBLOCKS) flags[idx << 5] = 0u;   // reset progress flags every launch (replay-safe)
    if (idx >= PBF_TOTAL) return;
    float v;
    if (idx < PBF_LAYERS) {
        int i = idx / PBF_PER_LAYER;
        int r = idx - i * PBF_PER_LAYER;
        if (r < 16384) {                  // gates A (128x128 = [f;g] x [left||right])
            int j = r & 7, l = (r >> 3) & 63, ks = (r >> 9) & 3, mt = r >> 11;
            int m = mt * 16 + (l & 15);
            int k = ks * 32 + ((l >> 4) << 3) + j;
            int o = m & 63, c = k & 63, half = k >> 6;
            const float* src = (m < 64) ? wf : wg;
            v = src[(((i * 64 + o) * 64 + c) << 1) + half];
        } else {                          // rs A (128x64 = [r;s] x c)
            int rr = r - 16384;
            int j = rr & 7, l = (rr >> 3) & 63, ks = (rr >> 9) & 1, mt = rr >> 10;
            int m = mt * 16 + (l & 15);
            int k = ks * 32 + ((l >> 4) << 3) + j;
            v = (m < 64) ? wr[(i * 64 + m) * 64 + k] : wsk[(i * 64 + (m - 64)) * 64 + k];
        }
    } else if (idx < PBF_LAYERS + 4096) { // W0 head (64x64)
        int rr = idx - PBF_LAYERS;
        int j = rr & 7, l = (rr >> 3) & 63, ks = (rr >> 9) & 1, mt = rr >> 10;
        int m = mt * 16 + (l & 15);
        int k = ks * 32 + ((l >> 4) << 3) + j;
        v = w0h[m * 64 + k];
    } else {                              // W1 head (256x64)
        int rr = idx - PBF_LAYERS - 4096;
        int j = rr & 7, l = (rr >> 3) & 63, ks = (rr >> 9) & 1, mt = rr >> 10;
        int m = mt * 16 + (l & 15);
        int k = ks * 32 + ((l >> 4) << 3) + j;
        v = w1h[m * 64 + k];
    }
    out[idx] = f2bf(v);
}

// ---------------------------------------------------------------- fused persistent kernel
// R15 (on R14, fused ~231us; weight-path theory confirmed 3x): stage the FULL
// 48KB layer panel (gates 32KB + res/skip 16KB) into LDS once per block per
// layer; res/skip af reads move from redundant per-wave L2 streams (~200cy
// exposed) to LDS (~12cy). Per-CU weight traffic drops another 96KB/layer.
// LDS: WALL 48KB + HT 16KB = 64KB static (limit); 2 blocks/CU = 128 <= 160KB.
// ZB aliases WALL's gates region (first 18KB, free after barrier B2); the RS
// region (32..48KB) is never aliased and persists through res/skip GEMM.
// Everything else identical to R14 (2-tile/wave af sharing, fp32 residual in
// regs, rcp activations, 4-deep halo ring, fence-free sc1/LLC, relaxed flags).
__global__ __launch_bounds__(256, 2) void wavenet_fused(
    const float* __restrict__ in, const float* __restrict__ w0v, const float* __restrict__ b0v,
    const ushort_t* __restrict__ pbf,
    const float* __restrict__ bf_all, const float* __restrict__ bg_all,
    const float* __restrict__ br_all, const float* __restrict__ bs_all,
    const float* __restrict__ alpha, const float* __restrict__ b_out0,
    const float* __restrict__ b_out1,
    ushort_t* __restrict__ HB, float* __restrict__ out, unsigned* flags)
{
    __shared__ alignas(16) ushort_t WALL[24576];    // 48 KB: gates 0..16383, RS 16384..24575
    __shared__ alignas(16) ushort_t HT[128 * 64];   // 16 KB bf16 H, single-buffered

    ushort_t* const ZB = WALL;                      // z staging aliases gates region (18KB <= 32KB)

    const int tid = threadIdx.x;
    const int l = tid & 63, w = tid >> 6;          // 4 waves
    const int l15 = l & 15, quad = l >> 4;
    const int bid = (int)blockIdx.x;
    const int blk = (bid & 7) * 64 + (bid >> 3);   // XCD-chunked swizzle
    const int tau0 = blk * 128;
    const int nloc0 = w * 32 + l15;                // wave's tile 0 row (0..127)
    const int nloc1 = nloc0 + 16;                  // wave's tile 1 row
    const int tauN0 = tau0 + nloc0;
    const int tauN1 = tau0 + nloc1;

// 16B bf16 granule g (0..7) of row r, XOR-swizzled by row (single HT buffer)
#define HTP(r, g) ((const uint4v*)((char*)HT + ((r) << 7) + ((((g) ^ ((r) & 7))) << 4)))
// u64 write slot for ch chunk mt*16+quad*4 of row r
#define HTW(r, mt, q) ((u64_t*)((char*)HT + ((r) << 7) + ((((2 * (mt) + ((q) >> 1)) ^ ((r) & 7))) << 4) + (((q) & 1) << 3)))

    // ---- init: thread owns rows nloc0/nloc1, ch chunks mt*16+quad*4; fp32 in
    //      hreg, bf16 into HT; row 127 published to halo ring buffer 0 (d_0=1)
    f32x4 hreg[4][2];
    #pragma unroll
    for (int nt = 0; nt < 2; ++nt) {
        int nloc = nt ? nloc1 : nloc0;
        float x = in[tau0 + nloc];
        #pragma unroll
        for (int mt = 0; mt < 4; ++mt) {
            int c0 = mt * 16 + quad * 4;
            f32x4 wv = *(const f32x4*)(w0v + c0);
            f32x4 bv = *(const f32x4*)(b0v + c0);
            #pragma unroll
            for (int r = 0; r < 4; ++r) hreg[mt][nt][r] = fmaf(wv[r], x, bv[r]);
            u64_t pk = pk4(hreg[mt][nt]);
            *HTW(nloc, mt, quad) = pk;
            if (nloc == 127) {
                ushort_t* dst = HB + (tau0 + 127) * 64 + c0;
                asm volatile("global_store_dwordx2 %0, %1, off sc1" :: "v"(dst), "v"(pk) : "memory");
            }
        }
    }
    asm volatile("s_waitcnt vmcnt(0)" ::: "memory");
    __syncthreads();
    if (tid == 0)
        __hip_atomic_store(&flags[blk << 5], 1u, __ATOMIC_RELAXED, __HIP_MEMORY_SCOPE_AGENT);

    f32x4 skip_acc[4][2];
    #pragma unroll
    for (int mt = 0; mt < 4; ++mt)
        #pragma unroll
        for (int nt = 0; nt < 2; ++nt)
            skip_acc[mt][nt] = (f32x4){0.0f, 0.0f, 0.0f, 0.0f};

    #pragma unroll 1
    for (int i = 0; i < NLAYERS; ++i) {
        const int d = 1 << (i >= 10 ? i - 10 : i);
        const int ip1 = i + 1;
        const int dnext = (ip1 < NLAYERS) ? (1 << (ip1 >= 10 ? ip1 - 10 : ip1)) : 0;
        const int hn = dnext > 128 ? 128 : dnext;      // rows to publish for next layer
        const int nleft = (d + 127) >> 7;              // producers needed (<=4)
        // anti-dep: buffer (i+1)%4 was last READ at layer i-3 by blocks b+k,
        // k <= ceil(d_{i-3}/128); they are done once flag >= (i-3)+2 = i-1.
        const int di3 = (i >= 3) ? (1 << ((i - 3) >= 10 ? i - 13 : i - 3)) : 0;
        const int nr3 = (di3 + 127) >> 7;
        const ushort_t* haloIn = HB + (unsigned)(i & 3) * HALO_USHORTS;
        ushort_t* haloOut = HB + (unsigned)((i + 1) & 3) * HALO_USHORTS;

        // ---- wait for neighbor progress (relaxed polls of LLC; no fences)
        if (w == 0) {
            int nb = -1; unsigned tgt = 0;
            if (l < 4) {
                int k = l + 1;
                if (k <= nleft) { nb = blk - k; tgt = (unsigned)(i + 1); }
            } else if (l < 8 && i >= 3 && i < NLAYERS - 1) {
                int k = l - 3;
                if (k <= nr3) { nb = blk + k; tgt = (unsigned)(i - 1); }
            }
            if (nb >= 0 && nb < NBLOCKS) {
                while (__hip_atomic_load(&flags[nb << 5], __ATOMIC_RELAXED,
                                         __HIP_MEMORY_SCOPE_AGENT) < tgt)
                    __builtin_amdgcn_s_sleep(1);
            }
        }
        __syncthreads();   // A: poll done; prev-layer HT writes + ZB reads ordered

        const ushort_t* PW = pbf + i * PBF_PER_LAYER;
        const float* bfb = bf_all + i * 64;
        const float* bgb = bg_all + i * 64;
        const float* brb = br_all + i * 64;
        const float* bsb = bs_all + i * 64;

        // ---- stage FULL 48KB panel into WALL: wave w copies its 12KB chunk
        {
            const char* gsrc = (const char*)PW + w * 12288;
            char* ldst = (char*)WALL + w * 12288;
            #pragma unroll
            for (int r = 0; r < 12; ++r)
                *(uint4v*)(ldst + (r << 10) + (l << 4)) =
                    *(const uint4v*)(gsrc + (r << 10) + (l << 4));
        }

        // ---- gate B operands per tile: left from halo (bf16 global) or HT;
        //      own from HT. Issue all global loads first, one waitcnt.
        int grow0 = tauN0 - d; if (grow0 < 0) grow0 = 0;
        int grow1 = tauN1 - d; if (grow1 < 0) grow1 = 0;
        bf16x8 bl[4][2];   // [ks][nt]; fully unrolled use => register-resident
        const bool hl0 = grow0 < tau0, hl1 = grow1 < tau0;
        if (hl0) {
            const ushort_t* hp = haloIn + grow0 * 64 + quad * 8;
            asm volatile(
                "global_load_dwordx4 %0, %2, off sc1\n\t"
                "global_load_dwordx4 %1, %2, off offset:64 sc1"
                : "=&v"(bl[0][0]), "=&v"(bl[1][0]) : "v"(hp) : "memory");
        }
        if (hl1) {
            const ushort_t* hp = haloIn + grow1 * 64 + quad * 8;
            asm volatile(
                "global_load_dwordx4 %0, %2, off sc1\n\t"
                "global_load_dwordx4 %1, %2, off offset:64 sc1"
                : "=&v"(bl[0][1]), "=&v"(bl[1][1]) : "v"(hp) : "memory");
        }
        if (!hl0) {
            int rl = grow0 - tau0;
            BF8 a0, a1; a0.u4 = *HTP(rl, quad); a1.u4 = *HTP(rl, 4 + quad);
            bl[0][0] = a0.v; bl[1][0] = a1.v;
        }
        if (!hl1) {
            int rl = grow1 - tau0;
            BF8 a0, a1; a0.u4 = *HTP(rl, quad); a1.u4 = *HTP(rl, 4 + quad);
            bl[0][1] = a0.v; bl[1][1] = a1.v;
        }
        {
            BF8 b0, b1, b2, b3;
            b0.u4 = *HTP(nloc0, quad); b1.u4 = *HTP(nloc0, 4 + quad);
            b2.u4 = *HTP(nloc1, quad); b3.u4 = *HTP(nloc1, 4 + quad);
            bl[2][0] = b0.v; bl[3][0] = b1.v;
            bl[2][1] = b2.v; bl[3][1] = b3.v;
        }
        asm volatile("s_waitcnt vmcnt(0) lgkmcnt(0)" ::: "memory");
        __builtin_amdgcn_sched_barrier(0);             // rule #18
        __syncthreads();   // B: staging ds_writes + all waves' HT reads done

        // ---- gates GEMM: af from LDS (WALL gates region), feeds BOTH tiles
        f32x4 acc[8][2];
        #pragma unroll
        for (int mt = 0; mt < 4; ++mt) {
            f32x4 bfv = *(const f32x4*)(bfb + mt * 16 + quad * 4);
            f32x4 bgv = *(const f32x4*)(bgb + mt * 16 + quad * 4);
            acc[mt][0] = bfv; acc[mt][1] = bfv;
            acc[mt + 4][0] = bgv; acc[mt + 4][1] = bgv;
        }
        #pragma unroll
        for (int ks = 0; ks < 4; ++ks) {
            #pragma unroll
            for (int mt = 0; mt < 8; ++mt) {
                BF8 af; af.u4 = *(const uint4v*)((const char*)WALL + ((((mt << 2) + ks) * 64 + l) << 4));
                acc[mt][0] = __builtin_amdgcn_mfma_f32_16x16x32_bf16(af.v, bl[ks][0], acc[mt][0], 0, 0, 0);
                acc[mt][1] = __builtin_amdgcn_mfma_f32_16x16x32_bf16(af.v, bl[ks][1], acc[mt][1], 0, 0, 0);
            }
        }
        __syncthreads();   // B2: all waves' gates-af reads done before ZB(=WALL) overwrite

        // ---- z = tanh(f)*sigmoid(g) -> ZB rows nloc0/nloc1 (wave-private)
        #pragma unroll
        for (int nt = 0; nt < 2; ++nt) {
            int nloc = nt ? nloc1 : nloc0;
            #pragma unroll
            for (int mt = 0; mt < 4; ++mt) {
                f32x4 z;
                #pragma unroll
                for (int r = 0; r < 4; ++r) {
                    float f = acc[mt][nt][r];
                    float g = acc[mt + 4][nt][r];
                    float e2 = __expf(2.0f * f);
                    float th = 1.0f - 2.0f * __builtin_amdgcn_rcpf(e2 + 1.0f);
                    float sg = __builtin_amdgcn_rcpf(1.0f + __expf(-g));
                    z[r] = th * sg;
                }
                *(u64_t*)(ZB + nloc * 72 + mt * 16 + quad * 4) = pk4(z);
            }
        }
        asm volatile("s_waitcnt lgkmcnt(0)" ::: "memory");
        __builtin_amdgcn_sched_barrier(0);

        // ---- res/skip GEMM, af from LDS (WALL RS region), shared across tiles
        f32x4 acc2[8][2];
        #pragma unroll
        for (int mt = 0; mt < 4; ++mt) {
            f32x4 brv = *(const f32x4*)(brb + mt * 16 + quad * 4);
            f32x4 bsv = *(const f32x4*)(bsb + mt * 16 + quad * 4);
            acc2[mt][0] = brv; acc2[mt][1] = brv;
            acc2[mt + 4][0] = bsv; acc2[mt + 4][1] = bsv;
        }
        #pragma unroll
        for (int ks = 0; ks < 2; ++ks) {
            BF8 t0, t1;
            t0.u4 = *(const uint4v*)(ZB + nloc0 * 72 + ks * 32 + quad * 8);
            t1.u4 = *(const uint4v*)(ZB + nloc1 * 72 + ks * 32 + quad * 8);
            #pragma unroll
            for (int mt = 0; mt < 8; ++mt) {
                BF8 af; af.u4 = *(const uint4v*)((const char*)WALL + 32768 + ((((mt << 1) + ks) * 64 + l) << 4));
                acc2[mt][0] = __builtin_amdgcn_mfma_f32_16x16x32_bf16(af.v, t0.v, acc2[mt][0], 0, 0, 0);
                acc2[mt][1] = __builtin_amdgcn_mfma_f32_16x16x32_bf16(af.v, t1.v, acc2[mt][1], 0, 0, 0);
            }
        }

        // ---- epilogue: hreg = res + right (fp32 regs); bf16 -> HT (+ halo)
        #pragma unroll
        for (int nt = 0; nt < 2; ++nt) {
            #pragma unroll
            for (int mt = 0; mt < 4; ++mt) {
                #pragma unroll
                for (int r = 0; r < 4; ++r) {
                    hreg[mt][nt][r] = acc2[mt][nt][r] + hreg[mt][nt][r];
                    skip_acc[mt][nt][r] += acc2[mt + 4][nt][r];
                }
            }
        }
        if (i < NLAYERS - 1) {
            #pragma unroll
            for (int nt = 0; nt < 2; ++nt) {
                int nloc = nt ? nloc1 : nloc0;
                #pragma unroll
                for (int mt = 0; mt < 4; ++mt) {
                    u64_t pk = pk4(hreg[mt][nt]);
                    *HTW(nloc, mt, quad) = pk;
                    if (nloc >= 128 - hn) {
                        ushort_t* dst = haloOut + (tau0 + nloc) * 64 + mt * 16 + quad * 4;
                        asm volatile("global_store_dwordx2 %0, %1, off sc1"
                                     :: "v"(dst), "v"(pk) : "memory");
                    }
                }
            }
        }

        // ---- publish layer completion (halo at LLC after vmcnt + barrier)
        asm volatile("s_waitcnt vmcnt(0)" ::: "memory");
        __syncthreads();   // C: all waves' halo stores drained; HT writes visible
        if (i < NLAYERS - 1 && tid == 0)
            __hip_atomic_store(&flags[blk << 5], (unsigned)(i + 2), __ATOMIC_RELAXED,
                               __HIP_MEMORY_SCOPE_AGENT);
    }

    // ---- output head (block-local; skip in regs; ZB rows wave-private)
    asm volatile("s_waitcnt lgkmcnt(0)" ::: "memory");   // last layer's ZB reads done
    #pragma unroll
    for (int nt = 0; nt < 2; ++nt) {
        int nloc = nt ? nloc1 : nloc0;
        #pragma unroll
        for (int mt = 0; mt < 4; ++mt) {
            f32x4 a = *(const f32x4*)(alpha + mt * 16 + quad * 4);
            f32x4 y;
            #pragma unroll
            for (int r = 0; r < 4; ++r) {
                float x = skip_acc[mt][nt][r];
                y[r] = x > 0.0f ? x : a[r] * x;
            }
            *(u64_t*)(ZB + nloc * 72 + mt * 16 + quad * 4) = pk4(y);
        }
    }
    asm volatile("s_waitcnt lgkmcnt(0)" ::: "memory");
    __builtin_amdgcn_sched_barrier(0);

    const ushort_t* PW0 = pbf + PBF_LAYERS;
    const ushort_t* PW1 = PW0 + 4096;

    // W0 GEMM (64x64), af shared across tiles
    f32x4 acc0[4][2];
    #pragma unroll
    for (int mt = 0; mt < 4; ++mt) {
        f32x4 b = *(const f32x4*)(b_out0 + mt * 16 + quad * 4);
        acc0[mt][0] = b; acc0[mt][1] = b;
    }
    #pragma unroll
    for (int ks = 0; ks < 2; ++ks) {
        BF8 t0, t1;
        t0.u4 = *(const uint4v*)(ZB + nloc0 * 72 + ks * 32 + quad * 8);
        t1.u4 = *(const uint4v*)(ZB + nloc1 * 72 + ks * 32 + quad * 8);
        #pragma unroll
        for (int mt = 0; mt < 4; ++mt) {
            BF8 af; af.u4 = *(const uint4v*)(PW0 + (((mt << 1) + ks) * 64 + l) * 8);
            acc0[mt][0] = __builtin_amdgcn_mfma_f32_16x16x32_bf16(af.v, t0.v, acc0[mt][0], 0, 0, 0);
            acc0[mt][1] = __builtin_amdgcn_mfma_f32_16x16x32_bf16(af.v, t1.v, acc0[mt][1], 0, 0, 0);
        }
    }
    asm volatile("s_waitcnt lgkmcnt(0)" ::: "memory");   // W0 reads done before overwrite

    // lrelu_alpha1 -> X1 back into ZB (wave-private rows)
    #pragma unroll
    for (int nt = 0; nt < 2; ++nt) {
        int nloc = nt ? nloc1 : nloc0;
        #pragma unroll
        for (int mt = 0; mt < 4; ++mt) {
            f32x4 a = *(const f32x4*)(alpha + 64 + mt * 16 + quad * 4);
            f32x4 y;
            #pragma unroll
            for (int r = 0; r < 4; ++r) {
                float x = acc0[mt][nt][r];
                y[r] = x > 0.0f ? x : a[r] * x;
            }
            *(u64_t*)(ZB + nloc * 72 + mt * 16 + quad * 4) = pk4(y);
        }
    }
    asm volatile("s_waitcnt lgkmcnt(0)" ::: "memory");
    __builtin_amdgcn_sched_barrier(0);

    // W1 GEMM (256x64), af shared across tiles
    f32x4 acc1[16][2];
    #pragma unroll
    for (int mt = 0; mt < 16; ++mt) {
        f32x4 b = *(const f32x4*)(b_out1 + mt * 16 + quad * 4);
        acc1[mt][0] = b; acc1[mt][1] = b;
    }
    #pragma unroll
    for (int ks = 0; ks < 2; ++ks) {
        BF8 t0, t1;
        t0.u4 = *(const uint4v*)(ZB + nloc0 * 72 + ks * 32 + quad * 8);
        t1.u4 = *(const uint4v*)(ZB + nloc1 * 72 + ks * 32 + quad * 8);
        #pragma unroll
        for (int mt = 0; mt < 16; ++mt) {
            BF8 af; af.u4 = *(const uint4v*)(PW1 + (((mt << 1) + ks) * 64 + l) * 8);
            acc1[mt][0] = __builtin_amdgcn_mfma_f32_16x16x32_bf16(af.v, t0.v, acc1[mt][0], 0, 0, 0);
            acc1[mt][1] = __builtin_amdgcn_mfma_f32_16x16x32_bf16(af.v, t1.v, acc1[mt][1], 0, 0, 0);
        }
    }

    #pragma unroll
    for (int nt = 0; nt < 2; ++nt) {
        int nloc = nt ? nloc1 : nloc0;
        int u = tau0 + nloc - OUT_START;
        if (u >= 0) {
            #pragma unroll
            for (int mt = 0; mt < 16; ++mt)
                #pragma unroll
                for (int r = 0; r < 4; ++r)
                    out[(mt * 16 + quad * 4 + r) * OUT_W + u] = acc1[mt][nt][r];
        }
    }
#undef HTP
#undef HTW
}

// ---------------------------------------------------------------- launch
extern "C" void kernel_launch(void* const* d_in, const int* in_sizes, int n_in,
                              void* d_out, int out_size, void* d_ws, size_t ws_size,
                              hipStream_t stream)
{
    const float* input  = (const float*)d_in[0];
    const float* w0     = (const float*)d_in[1];
    const float* b0     = (const float*)d_in[2];
    const float* wf     = (const float*)d_in[3];
    const float* bf     = (const float*)d_in[4];
    const float* wg     = (const float*)d_in[5];
    const float* bg     = (const float*)d_in[6];
    const float* wr     = (const float*)d_in[7];
    const float* br     = (const float*)d_in[8];
    const float* wsk    = (const float*)d_in[9];
    const float* bs     = (const float*)d_in[10];
    const float* alpha  = (const float*)d_in[11];
    const float* w_out0 = (const float*)d_in[12];
    const float* b_out0 = (const float*)d_in[13];
    const float* w_out1 = (const float*)d_in[14];
    const float* b_out1 = (const float*)d_in[15];
    float* outp = (float*)d_out;

    float* wsbase = (float*)d_ws;
    ushort_t* pbf = (ushort_t*)wsbase;
    ushort_t* HB = (ushort_t*)(wsbase + HALO_OFF);
    unsigned* flags = (unsigned*)(wsbase + FLAG_OFF);

    pack_mfma<<<PBF_TOTAL / 256, 256, 0, stream>>>(wf, wg, wr, wsk, w_out0, w_out1, pbf, flags);

    wavenet_fused<<<dim3(NBLOCKS), dim3(256), 0, stream>>>(
        input, w0, b0, pbf, bf, bg, br, bs, alpha, b_out0, b_out1,
        HB, outp, flags);
}